// Round 2
// baseline (261.087 us; speedup 1.0000x reference)
//
#include <hip/hip_runtime.h>
#include <hip/hip_bf16.h>
#include <math.h>

// ---- problem constants ----
#define NCAMS 6
#define BH_ 100
#define BW_ 100
#define CDIM 256
#define NQ_ 4000           // HG*WG = 100*40
#define HF_ 48
#define WF_ 80
#define HEADS_ 8
#define PTS_ 8
#define HD_ 32
#define HWV (HF_*WF_)      // 3840
#define M1_ (NCAMS*HWV)    // 23040
#define M2_ (NCAMS*NQ_)    // 24000
#define NOUT_ 10000        // BH*BW

#define SA 264             // LDS A-tile row stride in bf16 elems (528 B, 16B-aligned)

typedef __bf16 bf16_t;
typedef __bf16 bf16x8 __attribute__((ext_vector_type(8)));
typedef __bf16 bf16x4 __attribute__((ext_vector_type(4)));
typedef float  f32x4  __attribute__((ext_vector_type(4)));

static __device__ __forceinline__ f32x4 mfma16(bf16x8 a, bf16x8 b, f32x4 c) {
    return __builtin_amdgcn_mfma_f32_16x16x32_bf16(a, b, c, 0, 0, 0);
}

// K0: build bf16 transposed weights: WvT[256][256], WcombT[192][256]=[Woff|Watt]^T, WoutT[256][256]
__global__ __launch_bounds__(256) void k0_prep(const float* __restrict__ Wv,
                                               const float* __restrict__ Woff,
                                               const float* __restrict__ Watt,
                                               const float* __restrict__ Wout,
                                               bf16_t* __restrict__ WvT,
                                               bf16_t* __restrict__ WcombT,
                                               bf16_t* __restrict__ WoutT) {
    int b = blockIdx.x, k = threadIdx.x;
    if (b < 256) {
        WvT[b * 256 + k] = (bf16_t)Wv[k * 256 + b];
    } else if (b < 448) {
        int n = b - 256;
        float v = (n < 128) ? Woff[k * 128 + n] : Watt[k * 64 + (n - 128)];
        WcombT[n * 256 + k] = (bf16_t)v;
    } else {
        int n = b - 448;
        WoutT[n * 256 + k] = (bf16_t)Wout[k * 256 + n];
    }
}

// K1: vh[cam][head][hw][hd] (bf16) = value @ Wv + bv. MFMA, 64x256 tile per block.
__global__ __launch_bounds__(256) void k1_vproj(const float* __restrict__ value,
                                                const bf16_t* __restrict__ WvT,
                                                const float* __restrict__ bv,
                                                bf16_t* __restrict__ vh) {
    __shared__ __align__(16) bf16_t At[64 * SA];
    const int m0 = blockIdx.x * 64;           // row = cam*3840 + hw; 3840%64==0 -> same cam
    const int cam = m0 / HWV;
    const int hw0 = m0 - cam * HWV;
    for (int idx = threadIdx.x; idx < 64 * 64; idx += 256) {
        int r = idx >> 6, c4 = idx & 63;
        float4 v = ((const float4*)value)[((hw0 + r) * NCAMS + cam) * 64 + c4];
        bf16x4 pk; pk[0] = (bf16_t)v.x; pk[1] = (bf16_t)v.y; pk[2] = (bf16_t)v.z; pk[3] = (bf16_t)v.w;
        *(bf16x4*)(At + r * SA + c4 * 4) = pk;
    }
    __syncthreads();
    const int lane = threadIdx.x & 63, w = threadIdx.x >> 6;
    const int lr = lane & 15, lk = lane >> 4;
    f32x4 acc[4][4] = {};
    const bf16_t* a0 = At + lr * SA + lk * 8;
    const bf16_t* b0 = WvT + (w * 64 + lr) * 256 + lk * 8;
#pragma unroll 2
    for (int ks = 0; ks < 8; ++ks) {
        bf16x8 af[4], bf_[4];
#pragma unroll
        for (int m = 0; m < 4; ++m) af[m] = *(const bf16x8*)(a0 + m * 16 * SA + ks * 32);
#pragma unroll
        for (int n = 0; n < 4; ++n) bf_[n] = *(const bf16x8*)(b0 + n * 16 * 256 + ks * 32);
#pragma unroll
        for (int m = 0; m < 4; ++m)
#pragma unroll
            for (int n = 0; n < 4; ++n)
                acc[m][n] = mfma16(af[m], bf_[n], acc[m][n]);
    }
#pragma unroll
    for (int n = 0; n < 4; ++n) {
        int col = w * 64 + n * 16 + lr;
        int head = col >> 5, hd = col & 31;
        float bias = bv[col];
        bf16_t* dst = vh + (size_t)(cam * HEADS_ + head) * HWV * HD_ + hd;
#pragma unroll
        for (int m = 0; m < 4; ++m) {
            int hwb = hw0 + m * 16 + lk * 4;
#pragma unroll
            for (int j = 0; j < 4; ++j)
                dst[(hwb + j) * HD_] = (bf16_t)(acc[m][n][j] + bias);
        }
    }
}

// K2: gather q rows (nearest, align_corners=True) -> MFMA GEMM vs WcombT (N=192)
//     -> off (+boff) stores + fully in-register softmax over PTS via shfl_xor.
__global__ __launch_bounds__(256) void k2_offatt(const float* __restrict__ query,
                                                 const float* __restrict__ qpos,
                                                 const float* __restrict__ qgrid,
                                                 const bf16_t* __restrict__ WcombT,
                                                 const float* __restrict__ boff,
                                                 const float* __restrict__ batt,
                                                 float* __restrict__ off_ws,
                                                 float* __restrict__ att_ws) {
    __shared__ __align__(16) bf16_t At[64 * SA];
    __shared__ int rowpos[64];
    const int m0 = blockIdx.x * 64;
    if (threadIdx.x < 64) {
        int m = m0 + threadIdx.x;
        float gx = qgrid[m * 2 + 0], gy = qgrid[m * 2 + 1];
        float fx = rintf(__fmul_rn(__fmul_rn(__fadd_rn(gx, 1.0f), 0.5f), 99.0f));
        float fy = rintf(__fmul_rn(__fmul_rn(__fadd_rn(gy, 1.0f), 0.5f), 99.0f));
        bool valid = (fx >= 0.0f) && (fx <= 99.0f) && (fy >= 0.0f) && (fy <= 99.0f);
        rowpos[threadIdx.x] = valid ? ((int)fy * BW_ + (int)fx) : -1;
    }
    __syncthreads();
    const float4* q4 = (const float4*)query;
    const float4* p4 = (const float4*)qpos;
    for (int idx = threadIdx.x; idx < 64 * 64; idx += 256) {
        int r = idx >> 6, c4 = idx & 63;
        int p = rowpos[r];
        bf16x4 pk;
        if (p >= 0) {
            float4 a = q4[p * 64 + c4];
            float4 b = p4[p * 64 + c4];
            pk[0] = (bf16_t)(a.x + b.x); pk[1] = (bf16_t)(a.y + b.y);
            pk[2] = (bf16_t)(a.z + b.z); pk[3] = (bf16_t)(a.w + b.w);
        } else {
            pk[0] = (bf16_t)0.0f; pk[1] = (bf16_t)0.0f; pk[2] = (bf16_t)0.0f; pk[3] = (bf16_t)0.0f;
        }
        *(bf16x4*)(At + r * SA + c4 * 4) = pk;
    }
    __syncthreads();
    const int lane = threadIdx.x & 63, w = threadIdx.x >> 6;
    const int lr = lane & 15, lk = lane >> 4;
    const int wcol0 = w * 48;
    f32x4 acc[4][3] = {};
    const bf16_t* a0 = At + lr * SA + lk * 8;
    const bf16_t* b0 = WcombT + (wcol0 + lr) * 256 + lk * 8;
#pragma unroll 2
    for (int ks = 0; ks < 8; ++ks) {
        bf16x8 af[4], bf_[3];
#pragma unroll
        for (int m = 0; m < 4; ++m) af[m] = *(const bf16x8*)(a0 + m * 16 * SA + ks * 32);
#pragma unroll
        for (int n = 0; n < 3; ++n) bf_[n] = *(const bf16x8*)(b0 + n * 16 * 256 + ks * 32);
#pragma unroll
        for (int m = 0; m < 4; ++m)
#pragma unroll
            for (int n = 0; n < 3; ++n)
                acc[m][n] = mfma16(af[m], bf_[n], acc[m][n]);
    }
#pragma unroll
    for (int n = 0; n < 3; ++n) {
        const int colbase = wcol0 + n * 16;
        const int col = colbase + lr;
        if (colbase < 128) {                       // offset columns
            float bo = boff[col];
#pragma unroll
            for (int m = 0; m < 4; ++m)
#pragma unroll
                for (int j = 0; j < 4; ++j)
                    off_ws[(m0 + m * 16 + lk * 4 + j) * 128 + col] = acc[m][n][j] + bo;
        } else {                                    // attention logits -> softmax over 8 lanes
            float bt = batt[col - 128];
#pragma unroll
            for (int m = 0; m < 4; ++m)
#pragma unroll
                for (int j = 0; j < 4; ++j) {
                    float lg = acc[m][n][j] + bt;
                    float mx = lg;
                    mx = fmaxf(mx, __shfl_xor(mx, 1, 64));
                    mx = fmaxf(mx, __shfl_xor(mx, 2, 64));
                    mx = fmaxf(mx, __shfl_xor(mx, 4, 64));
                    float e = expf(lg - mx);
                    float s = e;
                    s += __shfl_xor(s, 1, 64);
                    s += __shfl_xor(s, 2, 64);
                    s += __shfl_xor(s, 4, 64);
                    att_ws[(m0 + m * 16 + lk * 4 + j) * 64 + (col - 128)] = e / s;
                }
        }
    }
}

// K3: bilinear deformable sampling + attention-weighted sum (f32 math, bf16 vh).
__global__ __launch_bounds__(256) void k3_sample(const bf16_t* __restrict__ vh,
                                                 const float* __restrict__ refp,
                                                 const float* __restrict__ off_ws,
                                                 const float* __restrict__ att_ws,
                                                 float* __restrict__ out_attn) {
    const int u = blockIdx.x * 8 + (threadIdx.x >> 5);   // (m)*8 + h, < 192000
    const int hd = threadIdx.x & 31;
    const int m = u >> 3;
    const int h = u & 7;
    const int cam = m / NQ_;
    const float rx = refp[m * 2 + 0];
    const float ry = refp[m * 2 + 1];
    const bf16_t* base = vh + (size_t)(cam * HEADS_ + h) * HWV * HD_;
    const float4* off4 = (const float4*)(off_ws + m * 128 + h * 16);
    const float4* att4 = (const float4*)(att_ws + m * 64 + h * 8);
    float4 o0 = off4[0], o1 = off4[1], o2 = off4[2], o3 = off4[3];
    float4 a0 = att4[0], a1 = att4[1];
    float offv[16] = {o0.x, o0.y, o0.z, o0.w, o1.x, o1.y, o1.z, o1.w,
                      o2.x, o2.y, o2.z, o2.w, o3.x, o3.y, o3.z, o3.w};
    float attv[8] = {a0.x, a0.y, a0.z, a0.w, a1.x, a1.y, a1.z, a1.w};
    float acc = 0.0f;
#pragma unroll
    for (int p = 0; p < PTS_; ++p) {
        float ax = rx * (float)WF_ + offv[p * 2 + 0] - 0.5f;
        float ay = ry * (float)HF_ + offv[p * 2 + 1] - 0.5f;
        float x0f = floorf(ax), y0f = floorf(ay);
        float wx = ax - x0f, wy = ay - y0f;
        int x0 = (int)x0f, y0 = (int)y0f;
        int x1 = x0 + 1, y1 = y0 + 1;
        bool vx0 = (x0 >= 0) && (x0 < WF_), vx1 = (x1 >= 0) && (x1 < WF_);
        bool vy0 = (y0 >= 0) && (y0 < HF_), vy1 = (y1 >= 0) && (y1 < HF_);
        int cx0 = min(max(x0, 0), WF_ - 1), cx1 = min(max(x1, 0), WF_ - 1);
        int cy0 = min(max(y0, 0), HF_ - 1), cy1 = min(max(y1, 0), HF_ - 1);
        float v00 = (vx0 && vy0) ? (float)base[(cy0 * WF_ + cx0) * HD_ + hd] : 0.0f;
        float v01 = (vx1 && vy0) ? (float)base[(cy0 * WF_ + cx1) * HD_ + hd] : 0.0f;
        float v10 = (vx0 && vy1) ? (float)base[(cy1 * WF_ + cx0) * HD_ + hd] : 0.0f;
        float v11 = (vx1 && vy1) ? (float)base[(cy1 * WF_ + cx1) * HD_ + hd] : 0.0f;
        float bil = (v00 * (1.0f - wx) + v01 * wx) * (1.0f - wy)
                  + (v10 * (1.0f - wx) + v11 * wx) * wy;
        acc += attv[p] * bil;
    }
    out_attn[m * CDIM + h * HD_ + hd] = acc;
}

// K4: restore-BEV nearest gather (2 overlaps summed) * counts -> MFMA GEMM vs WoutT
//     + bout + residual.
__global__ __launch_bounds__(256) void k4_restore(const float* __restrict__ out_attn,
                                                  const float* __restrict__ rgrid,
                                                  const float* __restrict__ counts,
                                                  const bf16_t* __restrict__ WoutT,
                                                  const float* __restrict__ bout,
                                                  const float* __restrict__ query,
                                                  float* __restrict__ out) {
    __shared__ __align__(16) bf16_t At[64 * SA];
    __shared__ int pos2[64][2];
    __shared__ float cnt[64];
    const int m0 = blockIdx.x * 64;
    if (threadIdx.x < 128) {
        int r = threadIdx.x >> 1, k = threadIdx.x & 1;
        int i = m0 + r;
        if (i < NOUT_) {
            int bh = i / 100, bw = i - bh * 100;
            int R = bh + k * BH_;
            float gx = rgrid[(R * 100 + bw) * 2 + 0], gy = rgrid[(R * 100 + bw) * 2 + 1];
            float fx = rintf(__fmul_rn(__fmul_rn(__fadd_rn(gx, 1.0f), 0.5f), 39.0f));
            float fy = rintf(__fmul_rn(__fmul_rn(__fadd_rn(gy, 1.0f), 0.5f), 599.0f));
            bool valid = (fx >= 0.0f) && (fx <= 39.0f) && (fy >= 0.0f) && (fy <= 599.0f);
            int ix = (int)fx, iy = (int)fy;
            int camr = iy / 100, hg = iy - camr * 100;
            pos2[r][k] = valid ? (camr * NQ_ + hg * 40 + ix) : -1;
            if (k == 0) cnt[r] = counts[i];
        } else {
            pos2[r][k] = -1;
            if (k == 0) cnt[r] = 0.0f;
        }
    }
    __syncthreads();
    const float4* oa4 = (const float4*)out_attn;
    for (int idx = threadIdx.x; idx < 64 * 64; idx += 256) {
        int r = idx >> 6, c4 = idx & 63;
        int p0 = pos2[r][0], p1 = pos2[r][1];
        float sx = 0.f, sy = 0.f, sz = 0.f, sw = 0.f;
        if (p0 >= 0) { float4 a = oa4[p0 * 64 + c4]; sx += a.x; sy += a.y; sz += a.z; sw += a.w; }
        if (p1 >= 0) { float4 a = oa4[p1 * 64 + c4]; sx += a.x; sy += a.y; sz += a.z; sw += a.w; }
        float c = cnt[r];
        bf16x4 pk; pk[0] = (bf16_t)(sx * c); pk[1] = (bf16_t)(sy * c);
        pk[2] = (bf16_t)(sz * c); pk[3] = (bf16_t)(sw * c);
        *(bf16x4*)(At + r * SA + c4 * 4) = pk;
    }
    __syncthreads();
    const int lane = threadIdx.x & 63, w = threadIdx.x >> 6;
    const int lr = lane & 15, lk = lane >> 4;
    f32x4 acc[4][4] = {};
    const bf16_t* a0 = At + lr * SA + lk * 8;
    const bf16_t* b0 = WoutT + (w * 64 + lr) * 256 + lk * 8;
#pragma unroll 2
    for (int ks = 0; ks < 8; ++ks) {
        bf16x8 af[4], bf_[4];
#pragma unroll
        for (int m = 0; m < 4; ++m) af[m] = *(const bf16x8*)(a0 + m * 16 * SA + ks * 32);
#pragma unroll
        for (int n = 0; n < 4; ++n) bf_[n] = *(const bf16x8*)(b0 + n * 16 * 256 + ks * 32);
#pragma unroll
        for (int m = 0; m < 4; ++m)
#pragma unroll
            for (int n = 0; n < 4; ++n)
                acc[m][n] = mfma16(af[m], bf_[n], acc[m][n]);
    }
#pragma unroll
    for (int n = 0; n < 4; ++n) {
        int col = w * 64 + n * 16 + lr;
        float bo = bout[col];
#pragma unroll
        for (int m = 0; m < 4; ++m)
#pragma unroll
            for (int j = 0; j < 4; ++j) {
                int row = m0 + m * 16 + lk * 4 + j;
                if (row < NOUT_)
                    out[row * CDIM + col] = acc[m][n][j] + bo + query[row * CDIM + col];
            }
    }
}

extern "C" void kernel_launch(void* const* d_in, const int* in_sizes, int n_in,
                              void* d_out, int out_size, void* d_ws, size_t ws_size,
                              hipStream_t stream) {
    (void)in_sizes; (void)n_in; (void)out_size; (void)ws_size;
    const float* query  = (const float*)d_in[0];
    const float* value  = (const float*)d_in[1];
    const float* qgrid  = (const float*)d_in[2];
    const float* rgrid  = (const float*)d_in[3];
    const float* refp   = (const float*)d_in[4];
    const float* counts = (const float*)d_in[5];
    const float* qpos   = (const float*)d_in[6];
    const float* Wv     = (const float*)d_in[7];
    const float* bv     = (const float*)d_in[8];
    const float* Woff   = (const float*)d_in[9];
    const float* boff   = (const float*)d_in[10];
    const float* Watt   = (const float*)d_in[11];
    const float* batt   = (const float*)d_in[12];
    const float* Wout   = (const float*)d_in[13];
    const float* bout   = (const float*)d_in[14];
    float* out = (float*)d_out;
    char* w8 = (char*)d_ws;

    bf16_t* vh      = (bf16_t*)(w8);                 // 5,898,240 bf16 = 11,796,480 B
    float* out_attn = (float*)(w8 + 11796480);       // 6,144,000 f32
    float* off_ws   = (float*)(w8 + 36372480);       // 3,072,000 f32
    float* att_ws   = (float*)(w8 + 48660480);       // 1,536,000 f32
    bf16_t* WvT     = (bf16_t*)(w8 + 54804480);      // 65,536 bf16
    bf16_t* WcombT  = (bf16_t*)(w8 + 54935552);      // 49,152 bf16
    bf16_t* WoutT   = (bf16_t*)(w8 + 55033856);      // 65,536 bf16  (end 55,164,928 B)

    hipLaunchKernelGGL(k0_prep,   dim3(704),      dim3(256), 0, stream, Wv, Woff, Watt, Wout,
                       WvT, WcombT, WoutT);
    hipLaunchKernelGGL(k1_vproj,  dim3(M1_ / 64), dim3(256), 0, stream, value, WvT, bv, vh);
    hipLaunchKernelGGL(k2_offatt, dim3(M2_ / 64), dim3(256), 0, stream, query, qpos, qgrid,
                       WcombT, boff, batt, off_ws, att_ws);
    hipLaunchKernelGGL(k3_sample, dim3(24000),    dim3(256), 0, stream, vh, refp, off_ws,
                       att_ws, out_attn);
    hipLaunchKernelGGL(k4_restore, dim3(157),     dim3(256), 0, stream, out_attn, rgrid, counts,
                       WoutT, bout, query, out);
}

// Round 3
// 119.009 us; speedup vs baseline: 2.1938x; 2.1938x over previous
//
#include <hip/hip_runtime.h>
#include <hip/hip_bf16.h>
#include <math.h>

// ---- problem constants ----
#define NCAMS 6
#define BH_ 100
#define BW_ 100
#define CDIM 256
#define NQ_ 4000           // HG*WG = 100*40
#define HF_ 48
#define WF_ 80
#define HEADS_ 8
#define PTS_ 8
#define HD_ 32
#define HWV (HF_*WF_)      // 3840
#define M1_ (NCAMS*HWV)    // 23040
#define M2_ (NCAMS*NQ_)    // 24000
#define NOUT_ 10000        // BH*BW

#define SA 264             // LDS A-tile row stride in bf16 elems (528 B, 16B-aligned)

typedef __bf16 bf16_t;
typedef __bf16 bf16x8 __attribute__((ext_vector_type(8)));
typedef __bf16 bf16x4 __attribute__((ext_vector_type(4)));
typedef float  f32x4  __attribute__((ext_vector_type(4)));

static __device__ __forceinline__ f32x4 mfma16(bf16x8 a, bf16x8 b, f32x4 c) {
    return __builtin_amdgcn_mfma_f32_16x16x32_bf16(a, b, c, 0, 0, 0);
}

// K0: build bf16 transposed weights: WvT[256][256], WcombT[192][256]=[Woff|Watt]^T, WoutT[256][256]
__global__ __launch_bounds__(256) void k0_prep(const float* __restrict__ Wv,
                                               const float* __restrict__ Woff,
                                               const float* __restrict__ Watt,
                                               const float* __restrict__ Wout,
                                               bf16_t* __restrict__ WvT,
                                               bf16_t* __restrict__ WcombT,
                                               bf16_t* __restrict__ WoutT) {
    int b = blockIdx.x, k = threadIdx.x;
    if (b < 256) {
        WvT[b * 256 + k] = (bf16_t)Wv[k * 256 + b];
    } else if (b < 448) {
        int n = b - 256;
        float v = (n < 128) ? Woff[k * 128 + n] : Watt[k * 64 + (n - 128)];
        WcombT[n * 256 + k] = (bf16_t)v;
    } else {
        int n = b - 448;
        WoutT[n * 256 + k] = (bf16_t)Wout[k * 256 + n];
    }
}

// K1: vh[cam][head][hw][hd] (bf16) = value @ Wv + bv. MFMA, 64x256 tile per block.
__global__ __launch_bounds__(256) void k1_vproj(const float* __restrict__ value,
                                                const bf16_t* __restrict__ WvT,
                                                const float* __restrict__ bv,
                                                bf16_t* __restrict__ vh) {
    __shared__ __align__(16) bf16_t At[64 * SA];
    const int m0 = blockIdx.x * 64;           // row = cam*3840 + hw; 3840%64==0 -> same cam
    const int cam = m0 / HWV;
    const int hw0 = m0 - cam * HWV;
    for (int idx = threadIdx.x; idx < 64 * 64; idx += 256) {
        int r = idx >> 6, c4 = idx & 63;
        float4 v = ((const float4*)value)[((hw0 + r) * NCAMS + cam) * 64 + c4];
        bf16x4 pk; pk[0] = (bf16_t)v.x; pk[1] = (bf16_t)v.y; pk[2] = (bf16_t)v.z; pk[3] = (bf16_t)v.w;
        *(bf16x4*)(At + r * SA + c4 * 4) = pk;
    }
    __syncthreads();
    const int lane = threadIdx.x & 63, w = threadIdx.x >> 6;
    const int lr = lane & 15, lk = lane >> 4;
    f32x4 acc[4][4] = {};
    const bf16_t* a0 = At + lr * SA + lk * 8;
    const bf16_t* b0 = WvT + (w * 64 + lr) * 256 + lk * 8;
#pragma unroll 2
    for (int ks = 0; ks < 8; ++ks) {
        bf16x8 af[4], bf_[4];
#pragma unroll
        for (int m = 0; m < 4; ++m) af[m] = *(const bf16x8*)(a0 + m * 16 * SA + ks * 32);
#pragma unroll
        for (int n = 0; n < 4; ++n) bf_[n] = *(const bf16x8*)(b0 + n * 16 * 256 + ks * 32);
#pragma unroll
        for (int m = 0; m < 4; ++m)
#pragma unroll
            for (int n = 0; n < 4; ++n)
                acc[m][n] = mfma16(af[m], bf_[n], acc[m][n]);
    }
#pragma unroll
    for (int n = 0; n < 4; ++n) {
        int col = w * 64 + n * 16 + lr;
        int head = col >> 5, hd = col & 31;
        float bias = bv[col];
        bf16_t* dst = vh + (size_t)(cam * HEADS_ + head) * HWV * HD_ + hd;
#pragma unroll
        for (int m = 0; m < 4; ++m) {
            int hwb = hw0 + m * 16 + lk * 4;
#pragma unroll
            for (int j = 0; j < 4; ++j)
                dst[(hwb + j) * HD_] = (bf16_t)(acc[m][n][j] + bias);
        }
    }
}

// K2: gather q rows (nearest, align_corners=True) -> MFMA GEMM vs WcombT (N=192)
//     -> off (+boff) stores + fully in-register softmax over PTS via shfl_xor.
__global__ __launch_bounds__(256) void k2_offatt(const float* __restrict__ query,
                                                 const float* __restrict__ qpos,
                                                 const float* __restrict__ qgrid,
                                                 const bf16_t* __restrict__ WcombT,
                                                 const float* __restrict__ boff,
                                                 const float* __restrict__ batt,
                                                 float* __restrict__ off_ws,
                                                 float* __restrict__ att_ws) {
    __shared__ __align__(16) bf16_t At[64 * SA];
    __shared__ int rowpos[64];
    const int m0 = blockIdx.x * 64;
    if (threadIdx.x < 64) {
        int m = m0 + threadIdx.x;
        float gx = qgrid[m * 2 + 0], gy = qgrid[m * 2 + 1];
        float fx = rintf(__fmul_rn(__fmul_rn(__fadd_rn(gx, 1.0f), 0.5f), 99.0f));
        float fy = rintf(__fmul_rn(__fmul_rn(__fadd_rn(gy, 1.0f), 0.5f), 99.0f));
        bool valid = (fx >= 0.0f) && (fx <= 99.0f) && (fy >= 0.0f) && (fy <= 99.0f);
        rowpos[threadIdx.x] = valid ? ((int)fy * BW_ + (int)fx) : -1;
    }
    __syncthreads();
    const float4* q4 = (const float4*)query;
    const float4* p4 = (const float4*)qpos;
    for (int idx = threadIdx.x; idx < 64 * 64; idx += 256) {
        int r = idx >> 6, c4 = idx & 63;
        int p = rowpos[r];
        bf16x4 pk;
        if (p >= 0) {
            float4 a = q4[p * 64 + c4];
            float4 b = p4[p * 64 + c4];
            pk[0] = (bf16_t)(a.x + b.x); pk[1] = (bf16_t)(a.y + b.y);
            pk[2] = (bf16_t)(a.z + b.z); pk[3] = (bf16_t)(a.w + b.w);
        } else {
            pk[0] = (bf16_t)0.0f; pk[1] = (bf16_t)0.0f; pk[2] = (bf16_t)0.0f; pk[3] = (bf16_t)0.0f;
        }
        *(bf16x4*)(At + r * SA + c4 * 4) = pk;
    }
    __syncthreads();
    const int lane = threadIdx.x & 63, w = threadIdx.x >> 6;
    const int lr = lane & 15, lk = lane >> 4;
    const int wcol0 = w * 48;
    f32x4 acc[4][3] = {};
    const bf16_t* a0 = At + lr * SA + lk * 8;
    const bf16_t* b0 = WcombT + (wcol0 + lr) * 256 + lk * 8;
#pragma unroll 2
    for (int ks = 0; ks < 8; ++ks) {
        bf16x8 af[4], bf_[3];
#pragma unroll
        for (int m = 0; m < 4; ++m) af[m] = *(const bf16x8*)(a0 + m * 16 * SA + ks * 32);
#pragma unroll
        for (int n = 0; n < 3; ++n) bf_[n] = *(const bf16x8*)(b0 + n * 16 * 256 + ks * 32);
#pragma unroll
        for (int m = 0; m < 4; ++m)
#pragma unroll
            for (int n = 0; n < 3; ++n)
                acc[m][n] = mfma16(af[m], bf_[n], acc[m][n]);
    }
#pragma unroll
    for (int n = 0; n < 3; ++n) {
        const int colbase = wcol0 + n * 16;
        const int col = colbase + lr;
        if (colbase < 128) {                       // offset columns
            float bo = boff[col];
#pragma unroll
            for (int m = 0; m < 4; ++m)
#pragma unroll
                for (int j = 0; j < 4; ++j)
                    off_ws[(m0 + m * 16 + lk * 4 + j) * 128 + col] = acc[m][n][j] + bo;
        } else {                                    // attention logits -> softmax over 8 lanes
            float bt = batt[col - 128];
#pragma unroll
            for (int m = 0; m < 4; ++m)
#pragma unroll
                for (int j = 0; j < 4; ++j) {
                    float lg = acc[m][n][j] + bt;
                    float mx = lg;
                    mx = fmaxf(mx, __shfl_xor(mx, 1, 64));
                    mx = fmaxf(mx, __shfl_xor(mx, 2, 64));
                    mx = fmaxf(mx, __shfl_xor(mx, 4, 64));
                    float e = expf(lg - mx);
                    float s = e;
                    s += __shfl_xor(s, 1, 64);
                    s += __shfl_xor(s, 2, 64);
                    s += __shfl_xor(s, 4, 64);
                    att_ws[(m0 + m * 16 + lk * 4 + j) * 64 + (col - 128)] = e / s;
                }
        }
    }
}

// K3: bilinear deformable sampling + attention-weighted sum.
// One unit = (m,h) handled by 4 lanes; lane j owns channels 8j..8j+7 (one bf16x8
// load per corner). OOB handled by zeroing weights (addresses always clamped).
__global__ __launch_bounds__(256) void k3_sample(const bf16_t* __restrict__ vh,
                                                 const float* __restrict__ refp,
                                                 const float* __restrict__ off_ws,
                                                 const float* __restrict__ att_ws,
                                                 float* __restrict__ out_attn) {
    const int t = blockIdx.x * 256 + threadIdx.x;
    const int u = t >> 2;            // unit index = m*8 + h, u < 192000
    const int j = t & 3;             // channel-octet
    const int m = u >> 3;
    const int h = u & 7;
    const int cam = m / NQ_;
    const float rx = refp[m * 2 + 0];
    const float ry = refp[m * 2 + 1];
    const bf16_t* base = vh + (size_t)(cam * HEADS_ + h) * HWV * HD_ + j * 8;
    const float4* off4 = (const float4*)(off_ws + m * 128 + h * 16);
    const float4* att4 = (const float4*)(att_ws + m * 64 + h * 8);
    float4 o0 = off4[0], o1 = off4[1], o2 = off4[2], o3 = off4[3];
    float4 a0 = att4[0], a1 = att4[1];
    float offv[16] = {o0.x, o0.y, o0.z, o0.w, o1.x, o1.y, o1.z, o1.w,
                      o2.x, o2.y, o2.z, o2.w, o3.x, o3.y, o3.z, o3.w};
    float attv[8] = {a0.x, a0.y, a0.z, a0.w, a1.x, a1.y, a1.z, a1.w};
    float acc[8] = {};
#pragma unroll
    for (int p = 0; p < PTS_; ++p) {
        float ax = fmaf(rx, (float)WF_, offv[p * 2 + 0] - 0.5f);
        float ay = fmaf(ry, (float)HF_, offv[p * 2 + 1] - 0.5f);
        float x0f = floorf(ax), y0f = floorf(ay);
        float wx = ax - x0f, wy = ay - y0f;
        float att = attv[p];
        // per-corner attention-folded weights, zeroed when that corner is OOB
        bool vx0 = (x0f >= 0.0f) && (x0f <= (float)(WF_ - 1));
        bool vx1 = (x0f >= -1.0f) && (x0f <= (float)(WF_ - 2));
        bool vy0 = (y0f >= 0.0f) && (y0f <= (float)(HF_ - 1));
        bool vy1 = (y0f >= -1.0f) && (y0f <= (float)(HF_ - 2));
        float aw00 = (vx0 && vy0) ? att * (1.0f - wx) * (1.0f - wy) : 0.0f;
        float aw01 = (vx1 && vy0) ? att * wx * (1.0f - wy) : 0.0f;
        float aw10 = (vx0 && vy1) ? att * (1.0f - wx) * wy : 0.0f;
        float aw11 = (vx1 && vy1) ? att * wx * wy : 0.0f;
        // clamped integer coords (always safe to load)
        int x0 = (int)fminf(fmaxf(x0f, 0.0f), (float)(WF_ - 1));
        int x1 = (int)fminf(fmaxf(x0f + 1.0f, 0.0f), (float)(WF_ - 1));
        int y0 = (int)fminf(fmaxf(y0f, 0.0f), (float)(HF_ - 1));
        int y1 = (int)fminf(fmaxf(y0f + 1.0f, 0.0f), (float)(HF_ - 1));
        bf16x8 c00 = *(const bf16x8*)(base + (y0 * WF_ + x0) * HD_);
        bf16x8 c01 = *(const bf16x8*)(base + (y0 * WF_ + x1) * HD_);
        bf16x8 c10 = *(const bf16x8*)(base + (y1 * WF_ + x0) * HD_);
        bf16x8 c11 = *(const bf16x8*)(base + (y1 * WF_ + x1) * HD_);
#pragma unroll
        for (int c = 0; c < 8; ++c) {
            acc[c] = fmaf(aw00, (float)c00[c],
                     fmaf(aw01, (float)c01[c],
                     fmaf(aw10, (float)c10[c],
                     fmaf(aw11, (float)c11[c], acc[c]))));
        }
    }
    float4* dst = (float4*)(out_attn + m * CDIM + h * HD_ + j * 8);
    dst[0] = make_float4(acc[0], acc[1], acc[2], acc[3]);
    dst[1] = make_float4(acc[4], acc[5], acc[6], acc[7]);
}

// K4: restore-BEV nearest gather (2 overlaps summed) * counts -> MFMA GEMM vs WoutT
//     + bout + residual.
__global__ __launch_bounds__(256) void k4_restore(const float* __restrict__ out_attn,
                                                  const float* __restrict__ rgrid,
                                                  const float* __restrict__ counts,
                                                  const bf16_t* __restrict__ WoutT,
                                                  const float* __restrict__ bout,
                                                  const float* __restrict__ query,
                                                  float* __restrict__ out) {
    __shared__ __align__(16) bf16_t At[64 * SA];
    __shared__ int pos2[64][2];
    __shared__ float cnt[64];
    const int m0 = blockIdx.x * 64;
    if (threadIdx.x < 128) {
        int r = threadIdx.x >> 1, k = threadIdx.x & 1;
        int i = m0 + r;
        if (i < NOUT_) {
            int bh = i / 100, bw = i - bh * 100;
            int R = bh + k * BH_;
            float gx = rgrid[(R * 100 + bw) * 2 + 0], gy = rgrid[(R * 100 + bw) * 2 + 1];
            float fx = rintf(__fmul_rn(__fmul_rn(__fadd_rn(gx, 1.0f), 0.5f), 39.0f));
            float fy = rintf(__fmul_rn(__fmul_rn(__fadd_rn(gy, 1.0f), 0.5f), 599.0f));
            bool valid = (fx >= 0.0f) && (fx <= 39.0f) && (fy >= 0.0f) && (fy <= 599.0f);
            int ix = (int)fx, iy = (int)fy;
            int camr = iy / 100, hg = iy - camr * 100;
            pos2[r][k] = valid ? (camr * NQ_ + hg * 40 + ix) : -1;
            if (k == 0) cnt[r] = counts[i];
        } else {
            pos2[r][k] = -1;
            if (k == 0) cnt[r] = 0.0f;
        }
    }
    __syncthreads();
    const float4* oa4 = (const float4*)out_attn;
    for (int idx = threadIdx.x; idx < 64 * 64; idx += 256) {
        int r = idx >> 6, c4 = idx & 63;
        int p0 = pos2[r][0], p1 = pos2[r][1];
        float sx = 0.f, sy = 0.f, sz = 0.f, sw = 0.f;
        if (p0 >= 0) { float4 a = oa4[p0 * 64 + c4]; sx += a.x; sy += a.y; sz += a.z; sw += a.w; }
        if (p1 >= 0) { float4 a = oa4[p1 * 64 + c4]; sx += a.x; sy += a.y; sz += a.z; sw += a.w; }
        float c = cnt[r];
        bf16x4 pk; pk[0] = (bf16_t)(sx * c); pk[1] = (bf16_t)(sy * c);
        pk[2] = (bf16_t)(sz * c); pk[3] = (bf16_t)(sw * c);
        *(bf16x4*)(At + r * SA + c4 * 4) = pk;
    }
    __syncthreads();
    const int lane = threadIdx.x & 63, w = threadIdx.x >> 6;
    const int lr = lane & 15, lk = lane >> 4;
    f32x4 acc[4][4] = {};
    const bf16_t* a0 = At + lr * SA + lk * 8;
    const bf16_t* b0 = WoutT + (w * 64 + lr) * 256 + lk * 8;
#pragma unroll 2
    for (int ks = 0; ks < 8; ++ks) {
        bf16x8 af[4], bf_[4];
#pragma unroll
        for (int m = 0; m < 4; ++m) af[m] = *(const bf16x8*)(a0 + m * 16 * SA + ks * 32);
#pragma unroll
        for (int n = 0; n < 4; ++n) bf_[n] = *(const bf16x8*)(b0 + n * 16 * 256 + ks * 32);
#pragma unroll
        for (int m = 0; m < 4; ++m)
#pragma unroll
            for (int n = 0; n < 4; ++n)
                acc[m][n] = mfma16(af[m], bf_[n], acc[m][n]);
    }
#pragma unroll
    for (int n = 0; n < 4; ++n) {
        int col = w * 64 + n * 16 + lr;
        float bo = bout[col];
#pragma unroll
        for (int m = 0; m < 4; ++m)
#pragma unroll
            for (int j = 0; j < 4; ++j) {
                int row = m0 + m * 16 + lk * 4 + j;
                if (row < NOUT_)
                    out[row * CDIM + col] = acc[m][n][j] + bo + query[row * CDIM + col];
            }
    }
}

extern "C" void kernel_launch(void* const* d_in, const int* in_sizes, int n_in,
                              void* d_out, int out_size, void* d_ws, size_t ws_size,
                              hipStream_t stream) {
    (void)in_sizes; (void)n_in; (void)out_size; (void)ws_size;
    const float* query  = (const float*)d_in[0];
    const float* value  = (const float*)d_in[1];
    const float* qgrid  = (const float*)d_in[2];
    const float* rgrid  = (const float*)d_in[3];
    const float* refp   = (const float*)d_in[4];
    const float* counts = (const float*)d_in[5];
    const float* qpos   = (const float*)d_in[6];
    const float* Wv     = (const float*)d_in[7];
    const float* bv     = (const float*)d_in[8];
    const float* Woff   = (const float*)d_in[9];
    const float* boff   = (const float*)d_in[10];
    const float* Watt   = (const float*)d_in[11];
    const float* batt   = (const float*)d_in[12];
    const float* Wout   = (const float*)d_in[13];
    const float* bout   = (const float*)d_in[14];
    float* out = (float*)d_out;
    char* w8 = (char*)d_ws;

    bf16_t* vh      = (bf16_t*)(w8);                 // 5,898,240 bf16 = 11,796,480 B
    float* out_attn = (float*)(w8 + 11796480);       // 6,144,000 f32
    float* off_ws   = (float*)(w8 + 36372480);       // 3,072,000 f32
    float* att_ws   = (float*)(w8 + 48660480);       // 1,536,000 f32
    bf16_t* WvT     = (bf16_t*)(w8 + 54804480);      // 65,536 bf16
    bf16_t* WcombT  = (bf16_t*)(w8 + 54935552);      // 49,152 bf16
    bf16_t* WoutT   = (bf16_t*)(w8 + 55033856);      // 65,536 bf16  (end 55,164,928 B)

    hipLaunchKernelGGL(k0_prep,   dim3(704),      dim3(256), 0, stream, Wv, Woff, Watt, Wout,
                       WvT, WcombT, WoutT);
    hipLaunchKernelGGL(k1_vproj,  dim3(M1_ / 64), dim3(256), 0, stream, value, WvT, bv, vh);
    hipLaunchKernelGGL(k2_offatt, dim3(M2_ / 64), dim3(256), 0, stream, query, qpos, qgrid,
                       WcombT, boff, batt, off_ws, att_ws);
    hipLaunchKernelGGL(k3_sample, dim3(3000),     dim3(256), 0, stream, vh, refp, off_ws,
                       att_ws, out_attn);
    hipLaunchKernelGGL(k4_restore, dim3(157),     dim3(256), 0, stream, out_attn, rgrid, counts,
                       WoutT, bout, query, out);
}

// Round 4
// 97.645 us; speedup vs baseline: 2.6738x; 1.2188x over previous
//
#include <hip/hip_runtime.h>
#include <hip/hip_bf16.h>
#include <math.h>

// ---- problem constants ----
#define NCAMS 6
#define BH_ 100
#define BW_ 100
#define CDIM 256
#define NQ_ 4000           // HG*WG = 100*40
#define HF_ 48
#define WF_ 80
#define HEADS_ 8
#define PTS_ 8
#define HD_ 32
#define HWV (HF_*WF_)      // 3840
#define M1_ (NCAMS*HWV)    // 23040
#define M2_ (NCAMS*NQ_)    // 24000
#define NOUT_ 10000        // BH*BW

#define SA 264             // padded LDS tile row stride in bf16 elems (528 B, 16B-aligned)

typedef __bf16 bf16_t;
typedef __bf16 bf16x8 __attribute__((ext_vector_type(8)));
typedef __bf16 bf16x4 __attribute__((ext_vector_type(4)));
typedef float  f32x4  __attribute__((ext_vector_type(4)));

static __device__ __forceinline__ f32x4 mfma16(bf16x8 a, bf16x8 b, f32x4 c) {
    return __builtin_amdgcn_mfma_f32_16x16x32_bf16(a, b, c, 0, 0, 0);
}

// K0: build bf16 transposed weights: WvT[256][256], WcombT[192][256]=[Woff|Watt]^T, WoutT[256][256]
__global__ __launch_bounds__(256) void k0_prep(const float* __restrict__ Wv,
                                               const float* __restrict__ Woff,
                                               const float* __restrict__ Watt,
                                               const float* __restrict__ Wout,
                                               bf16_t* __restrict__ WvT,
                                               bf16_t* __restrict__ WcombT,
                                               bf16_t* __restrict__ WoutT) {
    int b = blockIdx.x, k = threadIdx.x;
    if (b < 256) {
        WvT[b * 256 + k] = (bf16_t)Wv[k * 256 + b];
    } else if (b < 448) {
        int n = b - 256;
        float v = (n < 128) ? Woff[k * 128 + n] : Watt[k * 64 + (n - 128)];
        WcombT[n * 256 + k] = (bf16_t)v;
    } else {
        int n = b - 448;
        WoutT[n * 256 + k] = (bf16_t)Wout[k * 256 + n];
    }
}

// K1: vh[cam][head][hw][hd] (bf16) = value @ Wv + bv. MFMA, 32x256 tile, LDS-repacked
//     coalesced epilogue stores.
__global__ __launch_bounds__(256) void k1_vproj(const float* __restrict__ value,
                                                const bf16_t* __restrict__ WvT,
                                                const float* __restrict__ bv,
                                                bf16_t* __restrict__ vh) {
    __shared__ __align__(16) bf16_t At[32 * SA];
    const int m0 = blockIdx.x * 32;           // row = cam*3840 + hw; 3840%32==0 -> same cam
    const int cam = m0 / HWV;
    const int hw0 = m0 - cam * HWV;
    for (int idx = threadIdx.x; idx < 32 * 64; idx += 256) {
        int r = idx >> 6, c4 = idx & 63;
        float4 v = ((const float4*)value)[((hw0 + r) * NCAMS + cam) * 64 + c4];
        bf16x4 pk; pk[0] = (bf16_t)v.x; pk[1] = (bf16_t)v.y; pk[2] = (bf16_t)v.z; pk[3] = (bf16_t)v.w;
        *(bf16x4*)(At + r * SA + c4 * 4) = pk;
    }
    __syncthreads();
    const int lane = threadIdx.x & 63, w = threadIdx.x >> 6;
    const int lr = lane & 15, lk = lane >> 4;
    f32x4 acc[2][4] = {};
    const bf16_t* a0 = At + lr * SA + lk * 8;
    const bf16_t* b0 = WvT + (w * 64 + lr) * 256 + lk * 8;
#pragma unroll
    for (int ks = 0; ks < 8; ++ks) {
        bf16x8 af[2], bf_[4];
#pragma unroll
        for (int m = 0; m < 2; ++m) af[m] = *(const bf16x8*)(a0 + m * 16 * SA + ks * 32);
#pragma unroll
        for (int n = 0; n < 4; ++n) bf_[n] = *(const bf16x8*)(b0 + n * 16 * 256 + ks * 32);
#pragma unroll
        for (int m = 0; m < 2; ++m)
#pragma unroll
            for (int n = 0; n < 4; ++n)
                acc[m][n] = mfma16(af[m], bf_[n], acc[m][n]);
    }
    __syncthreads();                           // done reading At; reuse as C-tile
#pragma unroll
    for (int n = 0; n < 4; ++n) {
        int col = w * 64 + n * 16 + lr;
        float bias = bv[col];
#pragma unroll
        for (int m = 0; m < 2; ++m)
#pragma unroll
            for (int j = 0; j < 4; ++j)
                At[(m * 16 + lk * 4 + j) * SA + col] = (bf16_t)(acc[m][n][j] + bias);
    }
    __syncthreads();
    // coalesced store: 32 rows x 32 octets
    for (int idx = threadIdx.x; idx < 32 * 32; idx += 256) {
        int r = idx >> 5, g = idx & 31;
        int head = g >> 2, part = g & 3;
        bf16x8 v = *(const bf16x8*)(At + r * SA + g * 8);
        *(bf16x8*)(vh + ((size_t)(cam * HEADS_ + head) * HWV + hw0 + r) * HD_ + part * 8) = v;
    }
}

// K2: gather q rows (nearest, align_corners=True) -> MFMA GEMM vs WcombT (N=192)
//     -> off (+boff) stores + in-register softmax over PTS via shfl_xor. 32-row tiles.
__global__ __launch_bounds__(256) void k2_offatt(const float* __restrict__ query,
                                                 const float* __restrict__ qpos,
                                                 const float* __restrict__ qgrid,
                                                 const bf16_t* __restrict__ WcombT,
                                                 const float* __restrict__ boff,
                                                 const float* __restrict__ batt,
                                                 float* __restrict__ off_ws,
                                                 float* __restrict__ att_ws) {
    __shared__ __align__(16) bf16_t At[32 * SA];
    __shared__ int rowpos[32];
    const int m0 = blockIdx.x * 32;           // 4000%32==0 -> same cam
    if (threadIdx.x < 32) {
        int m = m0 + threadIdx.x;
        float gx = qgrid[m * 2 + 0], gy = qgrid[m * 2 + 1];
        float fx = rintf(__fmul_rn(__fmul_rn(__fadd_rn(gx, 1.0f), 0.5f), 99.0f));
        float fy = rintf(__fmul_rn(__fmul_rn(__fadd_rn(gy, 1.0f), 0.5f), 99.0f));
        bool valid = (fx >= 0.0f) && (fx <= 99.0f) && (fy >= 0.0f) && (fy <= 99.0f);
        rowpos[threadIdx.x] = valid ? ((int)fy * BW_ + (int)fx) : -1;
    }
    __syncthreads();
    const float4* q4 = (const float4*)query;
    const float4* p4 = (const float4*)qpos;
    for (int idx = threadIdx.x; idx < 32 * 64; idx += 256) {
        int r = idx >> 6, c4 = idx & 63;
        int p = rowpos[r];
        bf16x4 pk;
        if (p >= 0) {
            float4 a = q4[p * 64 + c4];
            float4 b = p4[p * 64 + c4];
            pk[0] = (bf16_t)(a.x + b.x); pk[1] = (bf16_t)(a.y + b.y);
            pk[2] = (bf16_t)(a.z + b.z); pk[3] = (bf16_t)(a.w + b.w);
        } else {
            pk[0] = (bf16_t)0.0f; pk[1] = (bf16_t)0.0f; pk[2] = (bf16_t)0.0f; pk[3] = (bf16_t)0.0f;
        }
        *(bf16x4*)(At + r * SA + c4 * 4) = pk;
    }
    __syncthreads();
    const int lane = threadIdx.x & 63, w = threadIdx.x >> 6;
    const int lr = lane & 15, lk = lane >> 4;
    const int wcol0 = w * 48;
    f32x4 acc[2][3] = {};
    const bf16_t* a0 = At + lr * SA + lk * 8;
    const bf16_t* b0 = WcombT + (wcol0 + lr) * 256 + lk * 8;
#pragma unroll
    for (int ks = 0; ks < 8; ++ks) {
        bf16x8 af[2], bf_[3];
#pragma unroll
        for (int m = 0; m < 2; ++m) af[m] = *(const bf16x8*)(a0 + m * 16 * SA + ks * 32);
#pragma unroll
        for (int n = 0; n < 3; ++n) bf_[n] = *(const bf16x8*)(b0 + n * 16 * 256 + ks * 32);
#pragma unroll
        for (int m = 0; m < 2; ++m)
#pragma unroll
            for (int n = 0; n < 3; ++n)
                acc[m][n] = mfma16(af[m], bf_[n], acc[m][n]);
    }
#pragma unroll
    for (int n = 0; n < 3; ++n) {
        const int colbase = wcol0 + n * 16;
        const int col = colbase + lr;
        if (colbase < 128) {                       // offset columns
            float bo = boff[col];
#pragma unroll
            for (int m = 0; m < 2; ++m)
#pragma unroll
                for (int j = 0; j < 4; ++j)
                    off_ws[(m0 + m * 16 + lk * 4 + j) * 128 + col] = acc[m][n][j] + bo;
        } else {                                    // attention logits -> softmax over 8 lanes
            float bt = batt[col - 128];
#pragma unroll
            for (int m = 0; m < 2; ++m)
#pragma unroll
                for (int j = 0; j < 4; ++j) {
                    float lg = acc[m][n][j] + bt;
                    float mx = lg;
                    mx = fmaxf(mx, __shfl_xor(mx, 1, 64));
                    mx = fmaxf(mx, __shfl_xor(mx, 2, 64));
                    mx = fmaxf(mx, __shfl_xor(mx, 4, 64));
                    float e = expf(lg - mx);
                    float s = e;
                    s += __shfl_xor(s, 1, 64);
                    s += __shfl_xor(s, 2, 64);
                    s += __shfl_xor(s, 4, 64);
                    att_ws[(m0 + m * 16 + lk * 4 + j) * 64 + (col - 128)] = e / s;
                }
        }
    }
}

// K3: bilinear deformable sampling + attention-weighted sum. 4 lanes per (m,h) unit,
//     lane j owns channels 8j..8j+7. XCD-chunked block swizzle for per-XCD L2 locality.
//     Output bf16.
__global__ __launch_bounds__(256) void k3_sample(const bf16_t* __restrict__ vh,
                                                 const float* __restrict__ refp,
                                                 const float* __restrict__ off_ws,
                                                 const float* __restrict__ att_ws,
                                                 bf16_t* __restrict__ out_attn) {
    // 3000 blocks = 8 XCDs x 375: logical id chunked so each XCD covers a
    // contiguous m-range (<= 2 cam slices -> <= 4 MiB vh working set per XCD L2)
    const int lb = (blockIdx.x & 7) * 375 + (blockIdx.x >> 3);
    const int t = lb * 256 + threadIdx.x;
    const int u = t >> 2;            // unit index = m*8 + h
    const int j = t & 3;             // channel-octet
    const int m = u >> 3;
    const int h = u & 7;
    const int cam = m / NQ_;
    const float rx = refp[m * 2 + 0];
    const float ry = refp[m * 2 + 1];
    const bf16_t* base = vh + (size_t)(cam * HEADS_ + h) * HWV * HD_ + j * 8;
    const float4* off4 = (const float4*)(off_ws + m * 128 + h * 16);
    const float4* att4 = (const float4*)(att_ws + m * 64 + h * 8);
    float4 o0 = off4[0], o1 = off4[1], o2 = off4[2], o3 = off4[3];
    float4 a0 = att4[0], a1 = att4[1];
    float offv[16] = {o0.x, o0.y, o0.z, o0.w, o1.x, o1.y, o1.z, o1.w,
                      o2.x, o2.y, o2.z, o2.w, o3.x, o3.y, o3.z, o3.w};
    float attv[8] = {a0.x, a0.y, a0.z, a0.w, a1.x, a1.y, a1.z, a1.w};
    float acc[8] = {};
#pragma unroll
    for (int p = 0; p < PTS_; ++p) {
        float ax = fmaf(rx, (float)WF_, offv[p * 2 + 0] - 0.5f);
        float ay = fmaf(ry, (float)HF_, offv[p * 2 + 1] - 0.5f);
        float x0f = floorf(ax), y0f = floorf(ay);
        float wx = ax - x0f, wy = ay - y0f;
        float att = attv[p];
        bool vx0 = (x0f >= 0.0f) && (x0f <= (float)(WF_ - 1));
        bool vx1 = (x0f >= -1.0f) && (x0f <= (float)(WF_ - 2));
        bool vy0 = (y0f >= 0.0f) && (y0f <= (float)(HF_ - 1));
        bool vy1 = (y0f >= -1.0f) && (y0f <= (float)(HF_ - 2));
        float aw00 = (vx0 && vy0) ? att * (1.0f - wx) * (1.0f - wy) : 0.0f;
        float aw01 = (vx1 && vy0) ? att * wx * (1.0f - wy) : 0.0f;
        float aw10 = (vx0 && vy1) ? att * (1.0f - wx) * wy : 0.0f;
        float aw11 = (vx1 && vy1) ? att * wx * wy : 0.0f;
        int x0 = (int)fminf(fmaxf(x0f, 0.0f), (float)(WF_ - 1));
        int x1 = (int)fminf(fmaxf(x0f + 1.0f, 0.0f), (float)(WF_ - 1));
        int y0 = (int)fminf(fmaxf(y0f, 0.0f), (float)(HF_ - 1));
        int y1 = (int)fminf(fmaxf(y0f + 1.0f, 0.0f), (float)(HF_ - 1));
        bf16x8 c00 = *(const bf16x8*)(base + (y0 * WF_ + x0) * HD_);
        bf16x8 c01 = *(const bf16x8*)(base + (y0 * WF_ + x1) * HD_);
        bf16x8 c10 = *(const bf16x8*)(base + (y1 * WF_ + x0) * HD_);
        bf16x8 c11 = *(const bf16x8*)(base + (y1 * WF_ + x1) * HD_);
#pragma unroll
        for (int c = 0; c < 8; ++c) {
            acc[c] = fmaf(aw00, (float)c00[c],
                     fmaf(aw01, (float)c01[c],
                     fmaf(aw10, (float)c10[c],
                     fmaf(aw11, (float)c11[c], acc[c]))));
        }
    }
    bf16x8 ov;
#pragma unroll
    for (int c = 0; c < 8; ++c) ov[c] = (bf16_t)acc[c];
    *(bf16x8*)(out_attn + (size_t)m * CDIM + h * HD_ + j * 8) = ov;
}

// K4: restore-BEV nearest gather (2 overlaps summed) * counts -> MFMA GEMM vs WoutT
//     + bout + residual. 32-row tiles.
__global__ __launch_bounds__(256) void k4_restore(const bf16_t* __restrict__ out_attn,
                                                  const float* __restrict__ rgrid,
                                                  const float* __restrict__ counts,
                                                  const bf16_t* __restrict__ WoutT,
                                                  const float* __restrict__ bout,
                                                  const float* __restrict__ query,
                                                  float* __restrict__ out) {
    __shared__ __align__(16) bf16_t At[32 * SA];
    __shared__ int pos2[32][2];
    __shared__ float cnt[32];
    const int m0 = blockIdx.x * 32;
    if (threadIdx.x < 64) {
        int r = threadIdx.x >> 1, k = threadIdx.x & 1;
        int i = m0 + r;
        if (i < NOUT_) {
            int bh = i / 100, bw = i - bh * 100;
            int R = bh + k * BH_;
            float gx = rgrid[(R * 100 + bw) * 2 + 0], gy = rgrid[(R * 100 + bw) * 2 + 1];
            float fx = rintf(__fmul_rn(__fmul_rn(__fadd_rn(gx, 1.0f), 0.5f), 39.0f));
            float fy = rintf(__fmul_rn(__fmul_rn(__fadd_rn(gy, 1.0f), 0.5f), 599.0f));
            bool valid = (fx >= 0.0f) && (fx <= 39.0f) && (fy >= 0.0f) && (fy <= 599.0f);
            int ix = (int)fx, iy = (int)fy;
            int camr = iy / 100, hg = iy - camr * 100;
            pos2[r][k] = valid ? (camr * NQ_ + hg * 40 + ix) : -1;
            if (k == 0) cnt[r] = counts[i];
        } else {
            pos2[r][k] = -1;
            if (k == 0) cnt[r] = 0.0f;
        }
    }
    __syncthreads();
    for (int idx = threadIdx.x; idx < 32 * 32; idx += 256) {
        int r = idx >> 5, g = idx & 31;
        int p0 = pos2[r][0], p1 = pos2[r][1];
        float s[8] = {};
        if (p0 >= 0) {
            bf16x8 a = *(const bf16x8*)(out_attn + (size_t)p0 * CDIM + g * 8);
#pragma unroll
            for (int c = 0; c < 8; ++c) s[c] += (float)a[c];
        }
        if (p1 >= 0) {
            bf16x8 a = *(const bf16x8*)(out_attn + (size_t)p1 * CDIM + g * 8);
#pragma unroll
            for (int c = 0; c < 8; ++c) s[c] += (float)a[c];
        }
        float cn = cnt[r];
        bf16x8 pk;
#pragma unroll
        for (int c = 0; c < 8; ++c) pk[c] = (bf16_t)(s[c] * cn);
        *(bf16x8*)(At + r * SA + g * 8) = pk;
    }
    __syncthreads();
    const int lane = threadIdx.x & 63, w = threadIdx.x >> 6;
    const int lr = lane & 15, lk = lane >> 4;
    f32x4 acc[2][4] = {};
    const bf16_t* a0 = At + lr * SA + lk * 8;
    const bf16_t* b0 = WoutT + (w * 64 + lr) * 256 + lk * 8;
#pragma unroll
    for (int ks = 0; ks < 8; ++ks) {
        bf16x8 af[2], bf_[4];
#pragma unroll
        for (int m = 0; m < 2; ++m) af[m] = *(const bf16x8*)(a0 + m * 16 * SA + ks * 32);
#pragma unroll
        for (int n = 0; n < 4; ++n) bf_[n] = *(const bf16x8*)(b0 + n * 16 * 256 + ks * 32);
#pragma unroll
        for (int m = 0; m < 2; ++m)
#pragma unroll
            for (int n = 0; n < 4; ++n)
                acc[m][n] = mfma16(af[m], bf_[n], acc[m][n]);
    }
#pragma unroll
    for (int n = 0; n < 4; ++n) {
        int col = w * 64 + n * 16 + lr;
        float bo = bout[col];
#pragma unroll
        for (int m = 0; m < 2; ++m)
#pragma unroll
            for (int j = 0; j < 4; ++j) {
                int row = m0 + m * 16 + lk * 4 + j;
                if (row < NOUT_)
                    out[row * CDIM + col] = acc[m][n][j] + bo + query[row * CDIM + col];
            }
    }
}

extern "C" void kernel_launch(void* const* d_in, const int* in_sizes, int n_in,
                              void* d_out, int out_size, void* d_ws, size_t ws_size,
                              hipStream_t stream) {
    (void)in_sizes; (void)n_in; (void)out_size; (void)ws_size;
    const float* query  = (const float*)d_in[0];
    const float* value  = (const float*)d_in[1];
    const float* qgrid  = (const float*)d_in[2];
    const float* rgrid  = (const float*)d_in[3];
    const float* refp   = (const float*)d_in[4];
    const float* counts = (const float*)d_in[5];
    const float* qpos   = (const float*)d_in[6];
    const float* Wv     = (const float*)d_in[7];
    const float* bv     = (const float*)d_in[8];
    const float* Woff   = (const float*)d_in[9];
    const float* boff   = (const float*)d_in[10];
    const float* Watt   = (const float*)d_in[11];
    const float* batt   = (const float*)d_in[12];
    const float* Wout   = (const float*)d_in[13];
    const float* bout   = (const float*)d_in[14];
    float* out = (float*)d_out;
    char* w8 = (char*)d_ws;

    bf16_t* vh       = (bf16_t*)(w8);                // 5,898,240 bf16 = 11,796,480 B
    bf16_t* out_attn = (bf16_t*)(w8 + 11796480);     // 6,144,000 bf16 = 12,288,000 B
    float* off_ws    = (float*)(w8 + 24084480);      // 3,072,000 f32
    float* att_ws    = (float*)(w8 + 36372480);      // 1,536,000 f32
    bf16_t* WvT      = (bf16_t*)(w8 + 42516480);     // 65,536 bf16
    bf16_t* WcombT   = (bf16_t*)(w8 + 42647552);     // 49,152 bf16
    bf16_t* WoutT    = (bf16_t*)(w8 + 42745856);     // 65,536 bf16  (end 42,876,928 B)

    hipLaunchKernelGGL(k0_prep,   dim3(704),      dim3(256), 0, stream, Wv, Woff, Watt, Wout,
                       WvT, WcombT, WoutT);
    hipLaunchKernelGGL(k1_vproj,  dim3(M1_ / 32), dim3(256), 0, stream, value, WvT, bv, vh);
    hipLaunchKernelGGL(k2_offatt, dim3(M2_ / 32), dim3(256), 0, stream, query, qpos, qgrid,
                       WcombT, boff, batt, off_ws, att_ws);
    hipLaunchKernelGGL(k3_sample, dim3(3000),     dim3(256), 0, stream, vh, refp, off_ws,
                       att_ws, out_attn);
    hipLaunchKernelGGL(k4_restore, dim3(313),     dim3(256), 0, stream, out_attn, rgrid, counts,
                       WoutT, bout, query, out);
}

// Round 5
// 95.252 us; speedup vs baseline: 2.7410x; 1.0251x over previous
//
#include <hip/hip_runtime.h>
#include <hip/hip_bf16.h>
#include <math.h>

// ---- problem constants ----
#define NCAMS 6
#define BH_ 100
#define BW_ 100
#define CDIM 256
#define NQ_ 4000           // HG*WG = 100*40
#define HF_ 48
#define WF_ 80
#define HEADS_ 8
#define PTS_ 8
#define HD_ 32
#define HWV (HF_*WF_)      // 3840
#define M1_ (NCAMS*HWV)    // 23040
#define M2_ (NCAMS*NQ_)    // 24000
#define NOUT_ 10000        // BH*BW

#define SA 264             // padded LDS tile row stride in bf16 elems (528 B, 16B-aligned)
#define SOFF 132           // padded off row stride (floats)
#define SATT 68            // padded att row stride (floats)

typedef __bf16 bf16_t;
typedef __bf16 bf16x8 __attribute__((ext_vector_type(8)));
typedef __bf16 bf16x4 __attribute__((ext_vector_type(4)));
typedef float  f32x4  __attribute__((ext_vector_type(4)));

static __device__ __forceinline__ f32x4 mfma16(bf16x8 a, bf16x8 b, f32x4 c) {
    return __builtin_amdgcn_mfma_f32_16x16x32_bf16(a, b, c, 0, 0, 0);
}

// K0: build bf16 transposed weights: WvT[256][256], WcombT[192][256]=[Woff|Watt]^T, WoutT[256][256]
__global__ __launch_bounds__(256) void k0_prep(const float* __restrict__ Wv,
                                               const float* __restrict__ Woff,
                                               const float* __restrict__ Watt,
                                               const float* __restrict__ Wout,
                                               bf16_t* __restrict__ WvT,
                                               bf16_t* __restrict__ WcombT,
                                               bf16_t* __restrict__ WoutT) {
    int b = blockIdx.x, k = threadIdx.x;
    if (b < 256) {
        WvT[b * 256 + k] = (bf16_t)Wv[k * 256 + b];
    } else if (b < 448) {
        int n = b - 256;
        float v = (n < 128) ? Woff[k * 128 + n] : Watt[k * 64 + (n - 128)];
        WcombT[n * 256 + k] = (bf16_t)v;
    } else {
        int n = b - 448;
        WoutT[n * 256 + k] = (bf16_t)Wout[k * 256 + n];
    }
}

// K1: vh[cam][head][hw][hd] (bf16) = value @ Wv + bv. MFMA, 32x256 tile, LDS-repacked
//     coalesced epilogue stores.
__global__ __launch_bounds__(256) void k1_vproj(const float* __restrict__ value,
                                                const bf16_t* __restrict__ WvT,
                                                const float* __restrict__ bv,
                                                bf16_t* __restrict__ vh) {
    __shared__ __align__(16) bf16_t At[32 * SA];
    const int m0 = blockIdx.x * 32;           // row = cam*3840 + hw; 3840%32==0 -> same cam
    const int cam = m0 / HWV;
    const int hw0 = m0 - cam * HWV;
    for (int idx = threadIdx.x; idx < 32 * 64; idx += 256) {
        int r = idx >> 6, c4 = idx & 63;
        float4 v = ((const float4*)value)[((hw0 + r) * NCAMS + cam) * 64 + c4];
        bf16x4 pk; pk[0] = (bf16_t)v.x; pk[1] = (bf16_t)v.y; pk[2] = (bf16_t)v.z; pk[3] = (bf16_t)v.w;
        *(bf16x4*)(At + r * SA + c4 * 4) = pk;
    }
    __syncthreads();
    const int lane = threadIdx.x & 63, w = threadIdx.x >> 6;
    const int lr = lane & 15, lk = lane >> 4;
    f32x4 acc[2][4] = {};
    const bf16_t* a0 = At + lr * SA + lk * 8;
    const bf16_t* b0 = WvT + (w * 64 + lr) * 256 + lk * 8;
#pragma unroll
    for (int ks = 0; ks < 8; ++ks) {
        bf16x8 af[2], bf_[4];
#pragma unroll
        for (int mm = 0; mm < 2; ++mm) af[mm] = *(const bf16x8*)(a0 + mm * 16 * SA + ks * 32);
#pragma unroll
        for (int n = 0; n < 4; ++n) bf_[n] = *(const bf16x8*)(b0 + n * 16 * 256 + ks * 32);
#pragma unroll
        for (int mm = 0; mm < 2; ++mm)
#pragma unroll
            for (int n = 0; n < 4; ++n)
                acc[mm][n] = mfma16(af[mm], bf_[n], acc[mm][n]);
    }
    __syncthreads();                           // done reading At; reuse as C-tile
#pragma unroll
    for (int n = 0; n < 4; ++n) {
        int col = w * 64 + n * 16 + lr;
        float bias = bv[col];
#pragma unroll
        for (int mm = 0; mm < 2; ++mm)
#pragma unroll
            for (int j = 0; j < 4; ++j)
                At[(mm * 16 + lk * 4 + j) * SA + col] = (bf16_t)(acc[mm][n][j] + bias);
    }
    __syncthreads();
    // coalesced store: 32 rows x 32 octets
    for (int idx = threadIdx.x; idx < 32 * 32; idx += 256) {
        int r = idx >> 5, g = idx & 31;
        int head = g >> 2, part = g & 3;
        bf16x8 v = *(const bf16x8*)(At + r * SA + g * 8);
        *(bf16x8*)(vh + ((size_t)(cam * HEADS_ + head) * HWV + hw0 + r) * HD_ + part * 8) = v;
    }
}

// K23: fused offsets/attention GEMM + bilinear deformable sampling.
// 16-row tile: gather q rows -> MFMA vs WcombT (N=192) -> off/att into LDS
// (aliased with the A-tile) -> sample 16 rows x 8 heads, write out_attn (bf16).
__global__ __launch_bounds__(256) void k23_offatt_sample(
        const float* __restrict__ query,
        const float* __restrict__ qpos,
        const float* __restrict__ qgrid,
        const bf16_t* __restrict__ WcombT,
        const float* __restrict__ boff,
        const float* __restrict__ batt,
        const float* __restrict__ refp,
        const bf16_t* __restrict__ vh,
        bf16_t* __restrict__ out_attn) {
    // union: phase1 A-tile overlaps phase2 off/att buffers
    __shared__ __align__(16) char u_lds[16 * SOFF * 4 + 16 * SATT * 4];   // 12800 B
    bf16_t* At   = (bf16_t*)u_lds;                 // 16*SA*2 = 8448 B
    float*  offs = (float*)u_lds;                  // 16*SOFF*4 = 8448 B
    float*  atts = (float*)(u_lds + 16 * SOFF * 4);// 16*SATT*4 = 4352 B
    __shared__ int rowpos[16];
    __shared__ float rref[16][2];

    // bijective XCD chunk swizzle: 1500 blocks = 8 XCDs, q=187 r=4
    const int orig = blockIdx.x;
    const int xcd = orig & 7, idx8 = orig >> 3;
    const int lb = (xcd < 4 ? xcd * 188 : 4 * 188 + (xcd - 4) * 187) + idx8;
    const int m0 = lb * 16;                        // 4000%16==0 -> same cam
    const int cam = m0 / NQ_;

    if (threadIdx.x < 16) {
        int m = m0 + threadIdx.x;
        float gx = qgrid[m * 2 + 0], gy = qgrid[m * 2 + 1];
        float fx = rintf(__fmul_rn(__fmul_rn(__fadd_rn(gx, 1.0f), 0.5f), 99.0f));
        float fy = rintf(__fmul_rn(__fmul_rn(__fadd_rn(gy, 1.0f), 0.5f), 99.0f));
        bool valid = (fx >= 0.0f) && (fx <= 99.0f) && (fy >= 0.0f) && (fy <= 99.0f);
        rowpos[threadIdx.x] = valid ? ((int)fy * BW_ + (int)fx) : -1;
    } else if (threadIdx.x < 48) {
        int t = threadIdx.x - 16;
        rref[t >> 1][t & 1] = refp[(m0 + (t >> 1)) * 2 + (t & 1)];
    }
    __syncthreads();
    const float4* q4 = (const float4*)query;
    const float4* p4 = (const float4*)qpos;
    {
        int idx = threadIdx.x;                     // 16*64 = 1024 stages, 4 per thread
#pragma unroll
        for (int it = 0; it < 4; ++it, idx += 256) {
            int r = idx >> 6, c4 = idx & 63;
            int p = rowpos[r];
            bf16x4 pk;
            if (p >= 0) {
                float4 a = q4[p * 64 + c4];
                float4 b = p4[p * 64 + c4];
                pk[0] = (bf16_t)(a.x + b.x); pk[1] = (bf16_t)(a.y + b.y);
                pk[2] = (bf16_t)(a.z + b.z); pk[3] = (bf16_t)(a.w + b.w);
            } else {
                pk[0] = (bf16_t)0.0f; pk[1] = (bf16_t)0.0f; pk[2] = (bf16_t)0.0f; pk[3] = (bf16_t)0.0f;
            }
            *(bf16x4*)(At + r * SA + c4 * 4) = pk;
        }
    }
    __syncthreads();
    const int lane = threadIdx.x & 63, w = threadIdx.x >> 6;
    const int lr = lane & 15, lk = lane >> 4;
    const int wcol0 = w * 48;
    f32x4 acc[3] = {};
    {
        const bf16_t* a0 = At + lr * SA + lk * 8;
        const bf16_t* b0 = WcombT + (wcol0 + lr) * 256 + lk * 8;
#pragma unroll
        for (int ks = 0; ks < 8; ++ks) {
            bf16x8 af = *(const bf16x8*)(a0 + ks * 32);
            bf16x8 bf_[3];
#pragma unroll
            for (int n = 0; n < 3; ++n) bf_[n] = *(const bf16x8*)(b0 + n * 16 * 256 + ks * 32);
#pragma unroll
            for (int n = 0; n < 3; ++n)
                acc[n] = mfma16(af, bf_[n], acc[n]);
        }
    }
    __syncthreads();                               // all At reads done; union -> offs/atts
#pragma unroll
    for (int n = 0; n < 3; ++n) {
        const int colbase = wcol0 + n * 16;
        const int col = colbase + lr;
        const int rloc = lk * 4;                   // +j
        if (colbase < 128) {                       // offset columns (+boff)
            float bo = boff[col];
#pragma unroll
            for (int j = 0; j < 4; ++j)
                offs[(rloc + j) * SOFF + col] = acc[n][j] + bo;
        } else {                                    // attention logits -> softmax over 8 lanes
            float bt = batt[col - 128];
#pragma unroll
            for (int j = 0; j < 4; ++j) {
                float lg = acc[n][j] + bt;
                float mx = lg;
                mx = fmaxf(mx, __shfl_xor(mx, 1, 64));
                mx = fmaxf(mx, __shfl_xor(mx, 2, 64));
                mx = fmaxf(mx, __shfl_xor(mx, 4, 64));
                float e = expf(lg - mx);
                float s = e;
                s += __shfl_xor(s, 1, 64);
                s += __shfl_xor(s, 2, 64);
                s += __shfl_xor(s, 4, 64);
                atts[(rloc + j) * SATT + (col - 128)] = e / s;
            }
        }
    }
    __syncthreads();
    // ---- phase 2: sampling. unit = (row, head); 4 lanes per unit (octets). ----
    const int j = threadIdx.x & 3;
#pragma unroll
    for (int rep = 0; rep < 2; ++rep) {
        const int unit = rep * 64 + (threadIdx.x >> 2);
        const int r = unit >> 3, h = unit & 7;
        const int m = m0 + r;
        const float rx = rref[r][0];
        const float ry = rref[r][1];
        const bf16_t* base = vh + (size_t)(cam * HEADS_ + h) * HWV * HD_ + j * 8;
        const float4* off4 = (const float4*)(offs + r * SOFF + h * 16);
        const float4* att4 = (const float4*)(atts + r * SATT + h * 8);
        float4 o0 = off4[0], o1 = off4[1], o2 = off4[2], o3 = off4[3];
        float4 a0 = att4[0], a1 = att4[1];
        float offv[16] = {o0.x, o0.y, o0.z, o0.w, o1.x, o1.y, o1.z, o1.w,
                          o2.x, o2.y, o2.z, o2.w, o3.x, o3.y, o3.z, o3.w};
        float attv[8] = {a0.x, a0.y, a0.z, a0.w, a1.x, a1.y, a1.z, a1.w};
        float acc2[8] = {};
#pragma unroll
        for (int p = 0; p < PTS_; ++p) {
            float ax = fmaf(rx, (float)WF_, offv[p * 2 + 0] - 0.5f);
            float ay = fmaf(ry, (float)HF_, offv[p * 2 + 1] - 0.5f);
            float x0f = floorf(ax), y0f = floorf(ay);
            float wx = ax - x0f, wy = ay - y0f;
            float att = attv[p];
            bool vx0 = (x0f >= 0.0f) && (x0f <= (float)(WF_ - 1));
            bool vx1 = (x0f >= -1.0f) && (x0f <= (float)(WF_ - 2));
            bool vy0 = (y0f >= 0.0f) && (y0f <= (float)(HF_ - 1));
            bool vy1 = (y0f >= -1.0f) && (y0f <= (float)(HF_ - 2));
            float aw00 = (vx0 && vy0) ? att * (1.0f - wx) * (1.0f - wy) : 0.0f;
            float aw01 = (vx1 && vy0) ? att * wx * (1.0f - wy) : 0.0f;
            float aw10 = (vx0 && vy1) ? att * (1.0f - wx) * wy : 0.0f;
            float aw11 = (vx1 && vy1) ? att * wx * wy : 0.0f;
            int x0 = (int)fminf(fmaxf(x0f, 0.0f), (float)(WF_ - 1));
            int x1 = (int)fminf(fmaxf(x0f + 1.0f, 0.0f), (float)(WF_ - 1));
            int y0 = (int)fminf(fmaxf(y0f, 0.0f), (float)(HF_ - 1));
            int y1 = (int)fminf(fmaxf(y0f + 1.0f, 0.0f), (float)(HF_ - 1));
            bf16x8 c00 = *(const bf16x8*)(base + (y0 * WF_ + x0) * HD_);
            bf16x8 c01 = *(const bf16x8*)(base + (y0 * WF_ + x1) * HD_);
            bf16x8 c10 = *(const bf16x8*)(base + (y1 * WF_ + x0) * HD_);
            bf16x8 c11 = *(const bf16x8*)(base + (y1 * WF_ + x1) * HD_);
#pragma unroll
            for (int c = 0; c < 8; ++c) {
                acc2[c] = fmaf(aw00, (float)c00[c],
                          fmaf(aw01, (float)c01[c],
                          fmaf(aw10, (float)c10[c],
                          fmaf(aw11, (float)c11[c], acc2[c]))));
            }
        }
        bf16x8 ov;
#pragma unroll
        for (int c = 0; c < 8; ++c) ov[c] = (bf16_t)acc2[c];
        *(bf16x8*)(out_attn + (size_t)m * CDIM + h * HD_ + j * 8) = ov;
    }
}

// K4: restore-BEV nearest gather (2 overlaps summed) * counts -> MFMA GEMM vs WoutT
//     + bout + residual. 32-row tiles.
__global__ __launch_bounds__(256) void k4_restore(const bf16_t* __restrict__ out_attn,
                                                  const float* __restrict__ rgrid,
                                                  const float* __restrict__ counts,
                                                  const bf16_t* __restrict__ WoutT,
                                                  const float* __restrict__ bout,
                                                  const float* __restrict__ query,
                                                  float* __restrict__ out) {
    __shared__ __align__(16) bf16_t At[32 * SA];
    __shared__ int pos2[32][2];
    __shared__ float cnt[32];
    const int m0 = blockIdx.x * 32;
    if (threadIdx.x < 64) {
        int r = threadIdx.x >> 1, k = threadIdx.x & 1;
        int i = m0 + r;
        if (i < NOUT_) {
            int bh = i / 100, bw = i - bh * 100;
            int R = bh + k * BH_;
            float gx = rgrid[(R * 100 + bw) * 2 + 0], gy = rgrid[(R * 100 + bw) * 2 + 1];
            float fx = rintf(__fmul_rn(__fmul_rn(__fadd_rn(gx, 1.0f), 0.5f), 39.0f));
            float fy = rintf(__fmul_rn(__fmul_rn(__fadd_rn(gy, 1.0f), 0.5f), 599.0f));
            bool valid = (fx >= 0.0f) && (fx <= 39.0f) && (fy >= 0.0f) && (fy <= 599.0f);
            int ix = (int)fx, iy = (int)fy;
            int camr = iy / 100, hg = iy - camr * 100;
            pos2[r][k] = valid ? (camr * NQ_ + hg * 40 + ix) : -1;
            if (k == 0) cnt[r] = counts[i];
        } else {
            pos2[r][k] = -1;
            if (k == 0) cnt[r] = 0.0f;
        }
    }
    __syncthreads();
    for (int idx = threadIdx.x; idx < 32 * 32; idx += 256) {
        int r = idx >> 5, g = idx & 31;
        int p0 = pos2[r][0], p1 = pos2[r][1];
        float s[8] = {};
        if (p0 >= 0) {
            bf16x8 a = *(const bf16x8*)(out_attn + (size_t)p0 * CDIM + g * 8);
#pragma unroll
            for (int c = 0; c < 8; ++c) s[c] += (float)a[c];
        }
        if (p1 >= 0) {
            bf16x8 a = *(const bf16x8*)(out_attn + (size_t)p1 * CDIM + g * 8);
#pragma unroll
            for (int c = 0; c < 8; ++c) s[c] += (float)a[c];
        }
        float cn = cnt[r];
        bf16x8 pk;
#pragma unroll
        for (int c = 0; c < 8; ++c) pk[c] = (bf16_t)(s[c] * cn);
        *(bf16x8*)(At + r * SA + g * 8) = pk;
    }
    __syncthreads();
    const int lane = threadIdx.x & 63, w = threadIdx.x >> 6;
    const int lr = lane & 15, lk = lane >> 4;
    f32x4 acc[2][4] = {};
    const bf16_t* a0 = At + lr * SA + lk * 8;
    const bf16_t* b0 = WoutT + (w * 64 + lr) * 256 + lk * 8;
#pragma unroll
    for (int ks = 0; ks < 8; ++ks) {
        bf16x8 af[2], bf_[4];
#pragma unroll
        for (int mm = 0; mm < 2; ++mm) af[mm] = *(const bf16x8*)(a0 + mm * 16 * SA + ks * 32);
#pragma unroll
        for (int n = 0; n < 4; ++n) bf_[n] = *(const bf16x8*)(b0 + n * 16 * 256 + ks * 32);
#pragma unroll
        for (int mm = 0; mm < 2; ++mm)
#pragma unroll
            for (int n = 0; n < 4; ++n)
                acc[mm][n] = mfma16(af[mm], bf_[n], acc[mm][n]);
    }
#pragma unroll
    for (int n = 0; n < 4; ++n) {
        int col = w * 64 + n * 16 + lr;
        float bo = bout[col];
#pragma unroll
        for (int mm = 0; mm < 2; ++mm)
#pragma unroll
            for (int j = 0; j < 4; ++j) {
                int row = m0 + mm * 16 + lk * 4 + j;
                if (row < NOUT_)
                    out[row * CDIM + col] = acc[mm][n][j] + bo + query[row * CDIM + col];
            }
    }
}

extern "C" void kernel_launch(void* const* d_in, const int* in_sizes, int n_in,
                              void* d_out, int out_size, void* d_ws, size_t ws_size,
                              hipStream_t stream) {
    (void)in_sizes; (void)n_in; (void)out_size; (void)ws_size;
    const float* query  = (const float*)d_in[0];
    const float* value  = (const float*)d_in[1];
    const float* qgrid  = (const float*)d_in[2];
    const float* rgrid  = (const float*)d_in[3];
    const float* refp   = (const float*)d_in[4];
    const float* counts = (const float*)d_in[5];
    const float* qpos   = (const float*)d_in[6];
    const float* Wv     = (const float*)d_in[7];
    const float* bv     = (const float*)d_in[8];
    const float* Woff   = (const float*)d_in[9];
    const float* boff   = (const float*)d_in[10];
    const float* Watt   = (const float*)d_in[11];
    const float* batt   = (const float*)d_in[12];
    const float* Wout   = (const float*)d_in[13];
    const float* bout   = (const float*)d_in[14];
    float* out = (float*)d_out;
    char* w8 = (char*)d_ws;

    bf16_t* vh       = (bf16_t*)(w8);                // 5,898,240 bf16 = 11,796,480 B
    bf16_t* out_attn = (bf16_t*)(w8 + 11796480);     // 6,144,000 bf16 = 12,288,000 B
    bf16_t* WvT      = (bf16_t*)(w8 + 24084480);     // 65,536 bf16
    bf16_t* WcombT   = (bf16_t*)(w8 + 24215552);     // 49,152 bf16
    bf16_t* WoutT    = (bf16_t*)(w8 + 24313856);     // 65,536 bf16  (end 24,444,928 B)

    hipLaunchKernelGGL(k0_prep,   dim3(704),      dim3(256), 0, stream, Wv, Woff, Watt, Wout,
                       WvT, WcombT, WoutT);
    hipLaunchKernelGGL(k1_vproj,  dim3(M1_ / 32), dim3(256), 0, stream, value, WvT, bv, vh);
    hipLaunchKernelGGL(k23_offatt_sample, dim3(M2_ / 16), dim3(256), 0, stream,
                       query, qpos, qgrid, WcombT, boff, batt, refp, vh, out_attn);
    hipLaunchKernelGGL(k4_restore, dim3(313),     dim3(256), 0, stream, out_attn, rgrid, counts,
                       WoutT, bout, query, out);
}

// Round 6
// 94.451 us; speedup vs baseline: 2.7643x; 1.0085x over previous
//
#include <hip/hip_runtime.h>
#include <hip/hip_bf16.h>
#include <math.h>

// ---- problem constants ----
#define NCAMS 6
#define BH_ 100
#define BW_ 100
#define CDIM 256
#define NQ_ 4000           // HG*WG = 100*40
#define HF_ 48
#define WF_ 80
#define HEADS_ 8
#define PTS_ 8
#define HD_ 32
#define HWV (HF_*WF_)      // 3840
#define M1_ (NCAMS*HWV)    // 23040
#define M2_ (NCAMS*NQ_)    // 24000
#define NOUT_ 10000        // BH*BW

#define SA 264             // padded LDS tile row stride in bf16 elems (528 B, 16B-aligned)
#define SOFF 132           // padded off row stride (floats)
#define SATT 68            // padded att row stride (floats)

typedef __bf16 bf16_t;
typedef __bf16 bf16x8 __attribute__((ext_vector_type(8)));
typedef __bf16 bf16x4 __attribute__((ext_vector_type(4)));
typedef float  f32x4  __attribute__((ext_vector_type(4)));

static __device__ __forceinline__ f32x4 mfma16(bf16x8 a, bf16x8 b, f32x4 c) {
    return __builtin_amdgcn_mfma_f32_16x16x32_bf16(a, b, c, 0, 0, 0);
}

// K0: bf16 transposed weights + qsum = (bf16)(query + query_pos).
// blocks: [0,256) WvT | [256,448) WcombT | [448,704) WoutT | [704,3204) qsum (4 rows each)
__global__ __launch_bounds__(256) void k0_prep(const float* __restrict__ Wv,
                                               const float* __restrict__ Woff,
                                               const float* __restrict__ Watt,
                                               const float* __restrict__ Wout,
                                               const float* __restrict__ query,
                                               const float* __restrict__ qpos,
                                               bf16_t* __restrict__ WvT,
                                               bf16_t* __restrict__ WcombT,
                                               bf16_t* __restrict__ WoutT,
                                               bf16_t* __restrict__ qsum) {
    int b = blockIdx.x, k = threadIdx.x;
    if (b < 256) {
        WvT[b * 256 + k] = (bf16_t)Wv[k * 256 + b];
    } else if (b < 448) {
        int n = b - 256;
        float v = (n < 128) ? Woff[k * 128 + n] : Watt[k * 64 + (n - 128)];
        WcombT[n * 256 + k] = (bf16_t)v;
    } else if (b < 704) {
        int n = b - 448;
        WoutT[n * 256 + k] = (bf16_t)Wout[k * 256 + n];
    } else {
        int row0 = (b - 704) * 4;                 // 4 rows per block
        int r = k >> 6, c4 = k & 63;
        int i = (row0 + r) * 64 + c4;             // float4 index
        float4 a = ((const float4*)query)[i];
        float4 p = ((const float4*)qpos)[i];
        bf16x4 pk;
        pk[0] = (bf16_t)(a.x + p.x); pk[1] = (bf16_t)(a.y + p.y);
        pk[2] = (bf16_t)(a.z + p.z); pk[3] = (bf16_t)(a.w + p.w);
        *(bf16x4*)(qsum + (size_t)i * 4) = pk;
    }
}

// K1: vh[cam][head][hw][hd] (bf16) = value @ Wv + bv. MFMA, 32x256 tile, LDS-repacked
//     coalesced epilogue stores.
__global__ __launch_bounds__(256) void k1_vproj(const float* __restrict__ value,
                                                const bf16_t* __restrict__ WvT,
                                                const float* __restrict__ bv,
                                                bf16_t* __restrict__ vh) {
    __shared__ __align__(16) bf16_t At[32 * SA];
    const int m0 = blockIdx.x * 32;           // row = cam*3840 + hw; 3840%32==0 -> same cam
    const int cam = m0 / HWV;
    const int hw0 = m0 - cam * HWV;
    for (int idx = threadIdx.x; idx < 32 * 64; idx += 256) {
        int r = idx >> 6, c4 = idx & 63;
        float4 v = ((const float4*)value)[((hw0 + r) * NCAMS + cam) * 64 + c4];
        bf16x4 pk; pk[0] = (bf16_t)v.x; pk[1] = (bf16_t)v.y; pk[2] = (bf16_t)v.z; pk[3] = (bf16_t)v.w;
        *(bf16x4*)(At + r * SA + c4 * 4) = pk;
    }
    __syncthreads();
    const int lane = threadIdx.x & 63, w = threadIdx.x >> 6;
    const int lr = lane & 15, lk = lane >> 4;
    f32x4 acc[2][4] = {};
    const bf16_t* a0 = At + lr * SA + lk * 8;
    const bf16_t* b0 = WvT + (w * 64 + lr) * 256 + lk * 8;
#pragma unroll
    for (int ks = 0; ks < 8; ++ks) {
        bf16x8 af[2], bf_[4];
#pragma unroll
        for (int mm = 0; mm < 2; ++mm) af[mm] = *(const bf16x8*)(a0 + mm * 16 * SA + ks * 32);
#pragma unroll
        for (int n = 0; n < 4; ++n) bf_[n] = *(const bf16x8*)(b0 + n * 16 * 256 + ks * 32);
#pragma unroll
        for (int mm = 0; mm < 2; ++mm)
#pragma unroll
            for (int n = 0; n < 4; ++n)
                acc[mm][n] = mfma16(af[mm], bf_[n], acc[mm][n]);
    }
    __syncthreads();                           // done reading At; reuse as C-tile
#pragma unroll
    for (int n = 0; n < 4; ++n) {
        int col = w * 64 + n * 16 + lr;
        float bias = bv[col];
#pragma unroll
        for (int mm = 0; mm < 2; ++mm)
#pragma unroll
            for (int j = 0; j < 4; ++j)
                At[(mm * 16 + lk * 4 + j) * SA + col] = (bf16_t)(acc[mm][n][j] + bias);
    }
    __syncthreads();
    // coalesced store: 32 rows x 32 octets
    for (int idx = threadIdx.x; idx < 32 * 32; idx += 256) {
        int r = idx >> 5, g = idx & 31;
        int head = g >> 2, part = g & 3;
        bf16x8 v = *(const bf16x8*)(At + r * SA + g * 8);
        *(bf16x8*)(vh + ((size_t)(cam * HEADS_ + head) * HWV + hw0 + r) * HD_ + part * 8) = v;
    }
}

// K23: fused offsets/attention GEMM + bilinear deformable sampling.
// Phase 2 processes TWO units per thread, interleaved in the point loop for 2x
// memory-level parallelism (unit B = unit A + 64: same head, row+8, same vh base).
__global__ __launch_bounds__(256) void k23_offatt_sample(
        const bf16_t* __restrict__ qsum,
        const float* __restrict__ qgrid,
        const bf16_t* __restrict__ WcombT,
        const float* __restrict__ boff,
        const float* __restrict__ batt,
        const float* __restrict__ refp,
        const bf16_t* __restrict__ vh,
        bf16_t* __restrict__ out_attn) {
    // union: phase1 A-tile overlaps phase2 off/att buffers
    __shared__ __align__(16) char u_lds[16 * SOFF * 4 + 16 * SATT * 4];   // 12800 B
    bf16_t* At   = (bf16_t*)u_lds;                 // 16*SA*2 = 8448 B
    float*  offs = (float*)u_lds;                  // 16*SOFF*4 = 8448 B
    float*  atts = (float*)(u_lds + 16 * SOFF * 4);// 16*SATT*4 = 4352 B
    __shared__ int rowpos[16];
    __shared__ float rref[16][2];

    // bijective XCD chunk swizzle: 1500 blocks = 8 XCDs, q=187 r=4
    const int orig = blockIdx.x;
    const int xcd = orig & 7, idx8 = orig >> 3;
    const int lb = (xcd < 4 ? xcd * 188 : 4 * 188 + (xcd - 4) * 187) + idx8;
    const int m0 = lb * 16;                        // 4000%16==0 -> same cam
    const int cam = m0 / NQ_;

    if (threadIdx.x < 16) {
        int m = m0 + threadIdx.x;
        float gx = qgrid[m * 2 + 0], gy = qgrid[m * 2 + 1];
        float fx = rintf(__fmul_rn(__fmul_rn(__fadd_rn(gx, 1.0f), 0.5f), 99.0f));
        float fy = rintf(__fmul_rn(__fmul_rn(__fadd_rn(gy, 1.0f), 0.5f), 99.0f));
        bool valid = (fx >= 0.0f) && (fx <= 99.0f) && (fy >= 0.0f) && (fy <= 99.0f);
        rowpos[threadIdx.x] = valid ? ((int)fy * BW_ + (int)fx) : -1;
    } else if (threadIdx.x < 48) {
        int t = threadIdx.x - 16;
        rref[t >> 1][t & 1] = refp[(m0 + (t >> 1)) * 2 + (t & 1)];
    }
    __syncthreads();
    // staging: 16 rows x 32 octets of bf16 qsum (2 per thread)
    {
        int idx = threadIdx.x;
#pragma unroll
        for (int it = 0; it < 2; ++it, idx += 256) {
            int r = idx >> 5, g = idx & 31;
            int p = rowpos[r];
            bf16x8 v;
            if (p >= 0) v = *(const bf16x8*)(qsum + (size_t)p * 256 + g * 8);
            else { bf16x8 z = {}; v = z; }
            *(bf16x8*)(At + r * SA + g * 8) = v;
        }
    }
    __syncthreads();
    const int lane = threadIdx.x & 63, w = threadIdx.x >> 6;
    const int lr = lane & 15, lk = lane >> 4;
    const int wcol0 = w * 48;
    f32x4 acc[3] = {};
    {
        const bf16_t* a0 = At + lr * SA + lk * 8;
        const bf16_t* b0 = WcombT + (wcol0 + lr) * 256 + lk * 8;
#pragma unroll
        for (int ks = 0; ks < 8; ++ks) {
            bf16x8 af = *(const bf16x8*)(a0 + ks * 32);
            bf16x8 bf_[3];
#pragma unroll
            for (int n = 0; n < 3; ++n) bf_[n] = *(const bf16x8*)(b0 + n * 16 * 256 + ks * 32);
#pragma unroll
            for (int n = 0; n < 3; ++n)
                acc[n] = mfma16(af, bf_[n], acc[n]);
        }
    }
    __syncthreads();                               // all At reads done; union -> offs/atts
#pragma unroll
    for (int n = 0; n < 3; ++n) {
        const int colbase = wcol0 + n * 16;
        const int col = colbase + lr;
        const int rloc = lk * 4;                   // +j
        if (colbase < 128) {                       // offset columns (+boff)
            float bo = boff[col];
#pragma unroll
            for (int j = 0; j < 4; ++j)
                offs[(rloc + j) * SOFF + col] = acc[n][j] + bo;
        } else {                                    // attention logits -> softmax over 8 lanes
            float bt = batt[col - 128];
#pragma unroll
            for (int j = 0; j < 4; ++j) {
                float lg = acc[n][j] + bt;
                float mx = lg;
                mx = fmaxf(mx, __shfl_xor(mx, 1, 64));
                mx = fmaxf(mx, __shfl_xor(mx, 2, 64));
                mx = fmaxf(mx, __shfl_xor(mx, 4, 64));
                float e = expf(lg - mx);
                float s = e;
                s += __shfl_xor(s, 1, 64);
                s += __shfl_xor(s, 2, 64);
                s += __shfl_xor(s, 4, 64);
                atts[(rloc + j) * SATT + (col - 128)] = e / s;
            }
        }
    }
    __syncthreads();
    // ---- phase 2: sampling. 2 interleaved units per thread (rows r0 and r0+8, same head) ----
    const int j = threadIdx.x & 3;
    const int u0 = threadIdx.x >> 2;               // 0..63
    const int r0 = u0 >> 3, h = u0 & 7, r1 = r0 + 8;
    const bf16_t* base = vh + (size_t)(cam * HEADS_ + h) * HWV * HD_ + j * 8;
    const float rxA = rref[r0][0], ryA = rref[r0][1];
    const float rxB = rref[r1][0], ryB = rref[r1][1];
    const float4* offA4 = (const float4*)(offs + r0 * SOFF + h * 16);
    const float4* offB4 = (const float4*)(offs + r1 * SOFF + h * 16);
    float oA[16], oB[16];
#pragma unroll
    for (int q = 0; q < 4; ++q) {
        float4 a = offA4[q], b = offB4[q];
        oA[q * 4 + 0] = a.x; oA[q * 4 + 1] = a.y; oA[q * 4 + 2] = a.z; oA[q * 4 + 3] = a.w;
        oB[q * 4 + 0] = b.x; oB[q * 4 + 1] = b.y; oB[q * 4 + 2] = b.z; oB[q * 4 + 3] = b.w;
    }
    const float* attA = atts + r0 * SATT + h * 8;
    const float* attB = atts + r1 * SATT + h * 8;
    float accA[8] = {}, accB[8] = {};
#pragma unroll
    for (int p = 0; p < PTS_; ++p) {
        // ---- unit A coords/weights ----
        float axA = fmaf(rxA, (float)WF_, oA[p * 2 + 0] - 0.5f);
        float ayA = fmaf(ryA, (float)HF_, oA[p * 2 + 1] - 0.5f);
        float xA0f = floorf(axA), yA0f = floorf(ayA);
        float wxA = axA - xA0f, wyA = ayA - yA0f;
        float attA_p = attA[p];
        bool vxA0 = (xA0f >= 0.0f) && (xA0f <= (float)(WF_ - 1));
        bool vxA1 = (xA0f >= -1.0f) && (xA0f <= (float)(WF_ - 2));
        bool vyA0 = (yA0f >= 0.0f) && (yA0f <= (float)(HF_ - 1));
        bool vyA1 = (yA0f >= -1.0f) && (yA0f <= (float)(HF_ - 2));
        float awA00 = (vxA0 && vyA0) ? attA_p * (1.0f - wxA) * (1.0f - wyA) : 0.0f;
        float awA01 = (vxA1 && vyA0) ? attA_p * wxA * (1.0f - wyA) : 0.0f;
        float awA10 = (vxA0 && vyA1) ? attA_p * (1.0f - wxA) * wyA : 0.0f;
        float awA11 = (vxA1 && vyA1) ? attA_p * wxA * wyA : 0.0f;
        int xA0 = (int)fminf(fmaxf(xA0f, 0.0f), (float)(WF_ - 1));
        int xA1 = (int)fminf(fmaxf(xA0f + 1.0f, 0.0f), (float)(WF_ - 1));
        int yA0 = (int)fminf(fmaxf(yA0f, 0.0f), (float)(HF_ - 1));
        int yA1 = (int)fminf(fmaxf(yA0f + 1.0f, 0.0f), (float)(HF_ - 1));
        // ---- unit B coords/weights ----
        float axB = fmaf(rxB, (float)WF_, oB[p * 2 + 0] - 0.5f);
        float ayB = fmaf(ryB, (float)HF_, oB[p * 2 + 1] - 0.5f);
        float xB0f = floorf(axB), yB0f = floorf(ayB);
        float wxB = axB - xB0f, wyB = ayB - yB0f;
        float attB_p = attB[p];
        bool vxB0 = (xB0f >= 0.0f) && (xB0f <= (float)(WF_ - 1));
        bool vxB1 = (xB0f >= -1.0f) && (xB0f <= (float)(WF_ - 2));
        bool vyB0 = (yB0f >= 0.0f) && (yB0f <= (float)(HF_ - 1));
        bool vyB1 = (yB0f >= -1.0f) && (yB0f <= (float)(HF_ - 2));
        float awB00 = (vxB0 && vyB0) ? attB_p * (1.0f - wxB) * (1.0f - wyB) : 0.0f;
        float awB01 = (vxB1 && vyB0) ? attB_p * wxB * (1.0f - wyB) : 0.0f;
        float awB10 = (vxB0 && vyB1) ? attB_p * (1.0f - wxB) * wyB : 0.0f;
        float awB11 = (vxB1 && vyB1) ? attB_p * wxB * wyB : 0.0f;
        int xB0 = (int)fminf(fmaxf(xB0f, 0.0f), (float)(WF_ - 1));
        int xB1 = (int)fminf(fmaxf(xB0f + 1.0f, 0.0f), (float)(WF_ - 1));
        int yB0 = (int)fminf(fmaxf(yB0f, 0.0f), (float)(HF_ - 1));
        int yB1 = (int)fminf(fmaxf(yB0f + 1.0f, 0.0f), (float)(HF_ - 1));
        // ---- 8 corner loads in flight together ----
        bf16x8 cA00 = *(const bf16x8*)(base + (yA0 * WF_ + xA0) * HD_);
        bf16x8 cA01 = *(const bf16x8*)(base + (yA0 * WF_ + xA1) * HD_);
        bf16x8 cA10 = *(const bf16x8*)(base + (yA1 * WF_ + xA0) * HD_);
        bf16x8 cA11 = *(const bf16x8*)(base + (yA1 * WF_ + xA1) * HD_);
        bf16x8 cB00 = *(const bf16x8*)(base + (yB0 * WF_ + xB0) * HD_);
        bf16x8 cB01 = *(const bf16x8*)(base + (yB0 * WF_ + xB1) * HD_);
        bf16x8 cB10 = *(const bf16x8*)(base + (yB1 * WF_ + xB0) * HD_);
        bf16x8 cB11 = *(const bf16x8*)(base + (yB1 * WF_ + xB1) * HD_);
#pragma unroll
        for (int c = 0; c < 8; ++c) {
            accA[c] = fmaf(awA00, (float)cA00[c],
                      fmaf(awA01, (float)cA01[c],
                      fmaf(awA10, (float)cA10[c],
                      fmaf(awA11, (float)cA11[c], accA[c]))));
            accB[c] = fmaf(awB00, (float)cB00[c],
                      fmaf(awB01, (float)cB01[c],
                      fmaf(awB10, (float)cB10[c],
                      fmaf(awB11, (float)cB11[c], accB[c]))));
        }
    }
    bf16x8 ovA, ovB;
#pragma unroll
    for (int c = 0; c < 8; ++c) { ovA[c] = (bf16_t)accA[c]; ovB[c] = (bf16_t)accB[c]; }
    *(bf16x8*)(out_attn + (size_t)(m0 + r0) * CDIM + h * HD_ + j * 8) = ovA;
    *(bf16x8*)(out_attn + (size_t)(m0 + r1) * CDIM + h * HD_ + j * 8) = ovB;
}

// K4: restore-BEV nearest gather (2 overlaps summed) * counts -> MFMA GEMM vs WoutT
//     + bout + residual. 32-row tiles.
__global__ __launch_bounds__(256) void k4_restore(const bf16_t* __restrict__ out_attn,
                                                  const float* __restrict__ rgrid,
                                                  const float* __restrict__ counts,
                                                  const bf16_t* __restrict__ WoutT,
                                                  const float* __restrict__ bout,
                                                  const float* __restrict__ query,
                                                  float* __restrict__ out) {
    __shared__ __align__(16) bf16_t At[32 * SA];
    __shared__ int pos2[32][2];
    __shared__ float cnt[32];
    const int m0 = blockIdx.x * 32;
    if (threadIdx.x < 64) {
        int r = threadIdx.x >> 1, k = threadIdx.x & 1;
        int i = m0 + r;
        if (i < NOUT_) {
            int bh = i / 100, bw = i - bh * 100;
            int R = bh + k * BH_;
            float gx = rgrid[(R * 100 + bw) * 2 + 0], gy = rgrid[(R * 100 + bw) * 2 + 1];
            float fx = rintf(__fmul_rn(__fmul_rn(__fadd_rn(gx, 1.0f), 0.5f), 39.0f));
            float fy = rintf(__fmul_rn(__fmul_rn(__fadd_rn(gy, 1.0f), 0.5f), 599.0f));
            bool valid = (fx >= 0.0f) && (fx <= 39.0f) && (fy >= 0.0f) && (fy <= 599.0f);
            int ix = (int)fx, iy = (int)fy;
            int camr = iy / 100, hg = iy - camr * 100;
            pos2[r][k] = valid ? (camr * NQ_ + hg * 40 + ix) : -1;
            if (k == 0) cnt[r] = counts[i];
        } else {
            pos2[r][k] = -1;
            if (k == 0) cnt[r] = 0.0f;
        }
    }
    __syncthreads();
    for (int idx = threadIdx.x; idx < 32 * 32; idx += 256) {
        int r = idx >> 5, g = idx & 31;
        int p0 = pos2[r][0], p1 = pos2[r][1];
        float s[8] = {};
        if (p0 >= 0) {
            bf16x8 a = *(const bf16x8*)(out_attn + (size_t)p0 * CDIM + g * 8);
#pragma unroll
            for (int c = 0; c < 8; ++c) s[c] += (float)a[c];
        }
        if (p1 >= 0) {
            bf16x8 a = *(const bf16x8*)(out_attn + (size_t)p1 * CDIM + g * 8);
#pragma unroll
            for (int c = 0; c < 8; ++c) s[c] += (float)a[c];
        }
        float cn = cnt[r];
        bf16x8 pk;
#pragma unroll
        for (int c = 0; c < 8; ++c) pk[c] = (bf16_t)(s[c] * cn);
        *(bf16x8*)(At + r * SA + g * 8) = pk;
    }
    __syncthreads();
    const int lane = threadIdx.x & 63, w = threadIdx.x >> 6;
    const int lr = lane & 15, lk = lane >> 4;
    f32x4 acc[2][4] = {};
    const bf16_t* a0 = At + lr * SA + lk * 8;
    const bf16_t* b0 = WoutT + (w * 64 + lr) * 256 + lk * 8;
#pragma unroll
    for (int ks = 0; ks < 8; ++ks) {
        bf16x8 af[2], bf_[4];
#pragma unroll
        for (int mm = 0; mm < 2; ++mm) af[mm] = *(const bf16x8*)(a0 + mm * 16 * SA + ks * 32);
#pragma unroll
        for (int n = 0; n < 4; ++n) bf_[n] = *(const bf16x8*)(b0 + n * 16 * 256 + ks * 32);
#pragma unroll
        for (int mm = 0; mm < 2; ++mm)
#pragma unroll
            for (int n = 0; n < 4; ++n)
                acc[mm][n] = mfma16(af[mm], bf_[n], acc[mm][n]);
    }
#pragma unroll
    for (int n = 0; n < 4; ++n) {
        int col = w * 64 + n * 16 + lr;
        float bo = bout[col];
#pragma unroll
        for (int mm = 0; mm < 2; ++mm)
#pragma unroll
            for (int j = 0; j < 4; ++j) {
                int row = m0 + mm * 16 + lk * 4 + j;
                if (row < NOUT_)
                    out[row * CDIM + col] = acc[mm][n][j] + bo + query[row * CDIM + col];
            }
    }
}

extern "C" void kernel_launch(void* const* d_in, const int* in_sizes, int n_in,
                              void* d_out, int out_size, void* d_ws, size_t ws_size,
                              hipStream_t stream) {
    (void)in_sizes; (void)n_in; (void)out_size; (void)ws_size;
    const float* query  = (const float*)d_in[0];
    const float* value  = (const float*)d_in[1];
    const float* qgrid  = (const float*)d_in[2];
    const float* rgrid  = (const float*)d_in[3];
    const float* refp   = (const float*)d_in[4];
    const float* counts = (const float*)d_in[5];
    const float* qpos   = (const float*)d_in[6];
    const float* Wv     = (const float*)d_in[7];
    const float* bv     = (const float*)d_in[8];
    const float* Woff   = (const float*)d_in[9];
    const float* boff   = (const float*)d_in[10];
    const float* Watt   = (const float*)d_in[11];
    const float* batt   = (const float*)d_in[12];
    const float* Wout   = (const float*)d_in[13];
    const float* bout   = (const float*)d_in[14];
    float* out = (float*)d_out;
    char* w8 = (char*)d_ws;

    bf16_t* vh       = (bf16_t*)(w8);                // 5,898,240 bf16 = 11,796,480 B
    bf16_t* out_attn = (bf16_t*)(w8 + 11796480);     // 6,144,000 bf16 = 12,288,000 B
    bf16_t* WvT      = (bf16_t*)(w8 + 24084480);     // 65,536 bf16
    bf16_t* WcombT   = (bf16_t*)(w8 + 24215552);     // 49,152 bf16
    bf16_t* WoutT    = (bf16_t*)(w8 + 24313856);     // 65,536 bf16
    bf16_t* qsum     = (bf16_t*)(w8 + 24444928);     // 2,560,000 bf16 = 5,120,000 B (end 29,564,928)

    hipLaunchKernelGGL(k0_prep,   dim3(3204),     dim3(256), 0, stream, Wv, Woff, Watt, Wout,
                       query, qpos, WvT, WcombT, WoutT, qsum);
    hipLaunchKernelGGL(k1_vproj,  dim3(M1_ / 32), dim3(256), 0, stream, value, WvT, bv, vh);
    hipLaunchKernelGGL(k23_offatt_sample, dim3(M2_ / 16), dim3(256), 0, stream,
                       qsum, qgrid, WcombT, boff, batt, refp, vh, out_attn);
    hipLaunchKernelGGL(k4_restore, dim3(313),     dim3(256), 0, stream, out_attn, rgrid, counts,
                       WoutT, bout, query, out);
}